// Round 13
// baseline (6363.664 us; speedup 1.0000x reference)
//
#include <hip/hip_runtime.h>
#include <hip/hip_bf16.h>

#define DMODEL 768
#define HD     64
#define NH     12
#define SEQL   81
#define BATCH  256
#define NTOK   (BATCH*SEQL)   /* 20736 */
#define FFDIM  3072
#define NLAYER 12

typedef __bf16 bf16x8 __attribute__((ext_vector_type(8)));
typedef float  f32x4  __attribute__((ext_vector_type(4)));
typedef unsigned short us8 __attribute__((ext_vector_type(8)));

__device__ __forceinline__ float bf2f(ushort u) {
    union { float f; unsigned u; } c; c.u = ((unsigned)u) << 16; return c.f;
}
__device__ __forceinline__ ushort f2bf(float f) {
    union { float f; unsigned u; } c; c.f = f;
    unsigned x = c.u;
    unsigned r = (x + 0x7fffu + ((x >> 16) & 1u)) >> 16;
    return (ushort)r;
}

#define GLL(gptr, lptr) __builtin_amdgcn_global_load_lds( \
    (const __attribute__((address_space(1))) void*)(gptr), \
    (__attribute__((address_space(3))) void*)(lptr), 16, 0, 0)

// ----------------------------- reductions -----------------------------
__device__ __forceinline__ float wave_sum(float v) {
#pragma unroll
    for (int o = 32; o > 0; o >>= 1) v += __shfl_down(v, o, 64);
    return v;
}

__device__ __forceinline__ void block_sum2_w4(float& a, float& b, float* red) {
    a = wave_sum(a); b = wave_sum(b);
    int lane = threadIdx.x & 63, wid = threadIdx.x >> 6;
    if (lane == 0) { red[wid] = a; red[4 + wid] = b; }
    __syncthreads();
    a = red[0] + red[1] + red[2] + red[3];
    b = red[4] + red[5] + red[6] + red[7];
    __syncthreads();
}
__device__ __forceinline__ void block_sum2_w3(float& a, float& b, float* red) {
    a = wave_sum(a); b = wave_sum(b);
    int lane = threadIdx.x & 63, wid = threadIdx.x >> 6;
    if (lane == 0) { red[wid] = a; red[3 + wid] = b; }
    __syncthreads();
    a = red[0] + red[1] + red[2];
    b = red[3] + red[4] + red[5];
    __syncthreads();
}

// ----------------------------- embedding + LN (bf16 out) --------------------
__global__ __launch_bounds__(256) void embed_ln_kernel(
    const int* __restrict__ ids, const float* __restrict__ wemb,
    const float* __restrict__ pemb, const float* __restrict__ g,
    const float* __restrict__ b, ushort* __restrict__ outb) {
    __shared__ float red[8];
    int tok = blockIdx.x;
    int s = tok % SEQL;
    long base = (long)ids[tok] * DMODEL;
    float vals[3];
    float sum = 0.f, sq = 0.f;
#pragma unroll
    for (int i = 0; i < 3; ++i) {
        int c = threadIdx.x + i * 256;
        float x = wemb[base + c] + pemb[s * DMODEL + c];
        vals[i] = x; sum += x; sq += x * x;
    }
    block_sum2_w4(sum, sq, red);
    float mean = sum * (1.0f / DMODEL);
    float inv = rsqrtf(sq * (1.0f / DMODEL) - mean * mean + 1e-5f);
#pragma unroll
    for (int i = 0; i < 3; ++i) {
        int c = threadIdx.x + i * 256;
        float y = (vals[i] - mean) * inv * g[c] + b[c];
        outb[(size_t)tok * DMODEL + c] = f2bf(y);
    }
}

// hb = bf16(LN(hb + r)); bf16 residual stream. 192 threads, ushort4.
__global__ __launch_bounds__(192) void add_ln_kernel(
    ushort* __restrict__ hb, const ushort* __restrict__ r,
    const float* __restrict__ g, const float* __restrict__ b) {
    __shared__ float red[6];
    size_t base = (size_t)blockIdx.x * DMODEL;
    int c = threadIdx.x * 4;
    ushort4 hv = *(const ushort4*)(hb + base + c);
    ushort4 rv = *(const ushort4*)(r + base + c);
    float vals[4];
    vals[0] = bf2f(hv.x) + bf2f(rv.x); vals[1] = bf2f(hv.y) + bf2f(rv.y);
    vals[2] = bf2f(hv.z) + bf2f(rv.z); vals[3] = bf2f(hv.w) + bf2f(rv.w);
    float sum = 0.f, sq = 0.f;
#pragma unroll
    for (int i = 0; i < 4; ++i) { sum += vals[i]; sq += vals[i] * vals[i]; }
    block_sum2_w3(sum, sq, red);
    float mean = sum * (1.0f / DMODEL);
    float inv = rsqrtf(sq * (1.0f / DMODEL) - mean * mean + 1e-5f);
    float4 gv = *(const float4*)(g + c);
    float4 bv = *(const float4*)(b + c);
    ushort4 ov;
    ov.x = f2bf((vals[0] - mean) * inv * gv.x + bv.x);
    ov.y = f2bf((vals[1] - mean) * inv * gv.y + bv.y);
    ov.z = f2bf((vals[2] - mean) * inv * gv.z + bv.z);
    ov.w = f2bf((vals[3] - mean) * inv * gv.w + bv.w);
    *(ushort4*)(hb + base + c) = ov;
}

// ----------------------------- weight conversion (per layer, fused) -----------
#define SQ1 589824                 /* 768*768 */
#define SQ2 2359296                /* 768*3072 */
#define CW_TOTAL (4*SQ1 + 2*SQ2 + 2304)
__global__ __launch_bounds__(256) void convw_layer(
    const float* __restrict__ wq, const float* __restrict__ wk,
    const float* __restrict__ wv, const float* __restrict__ wo,
    const float* __restrict__ w1, const float* __restrict__ w2,
    const float* __restrict__ bq, const float* __restrict__ bk,
    const float* __restrict__ bvp,
    ushort* __restrict__ qkvw, ushort* __restrict__ wob,
    ushort* __restrict__ w1b, ushort* __restrict__ w2b,
    float* __restrict__ cbias) {
    for (int i = blockIdx.x * 256 + threadIdx.x; i < CW_TOTAL; i += gridDim.x * 256) {
        if (i < 3 * SQ1) {
            int widx = i / SQ1, j = i - widx * SQ1;
            const float* src = widx == 0 ? wq : (widx == 1 ? wk : wv);
            int k = j / 768, n = j - k * 768;
            qkvw[(size_t)(k >> 3) * 2304 * 8 + (widx * 768 + n) * 8 + (k & 7)] = f2bf(src[j]);
        } else if (i < 4 * SQ1) {
            int j = i - 3 * SQ1;
            int k = j / 768, n = j - k * 768;
            wob[(size_t)(k >> 3) * 768 * 8 + n * 8 + (k & 7)] = f2bf(wo[j]);
        } else if (i < 4 * SQ1 + SQ2) {
            int j = i - 4 * SQ1;
            int k = j / 3072, n = j - k * 3072;
            w1b[(size_t)(k >> 3) * 3072 * 8 + n * 8 + (k & 7)] = f2bf(w1[j]);
        } else if (i < 4 * SQ1 + 2 * SQ2) {
            int j = i - 4 * SQ1 - SQ2;
            int k = j / 768, n = j - k * 768;
            w2b[(size_t)(k >> 3) * 768 * 8 + n * 8 + (k & 7)] = f2bf(w2[j]);
        } else {
            int j = i - 4 * SQ1 - 2 * SQ2;
            cbias[j] = j < 768 ? bq[j] : (j < 1536 ? bk[j - 768] : bvp[j - 1536]);
        }
    }
}

// conv0 weights: w[o][c][kk] fp32 -> dst[kk][(c>>3)*1024 + o*8 + (c&7)] bf16
__global__ __launch_bounds__(256) void convw_c0(
    const float* __restrict__ w, ushort* __restrict__ dst) {
    int idx = blockIdx.x * 256 + threadIdx.x;
    if (idx >= 128 * 768 * 8) return;
    int o = idx / 6144, rem = idx - o * 6144, c = rem >> 3, kk = rem & 7;
    dst[(size_t)kk * 98304 + (size_t)(c >> 3) * 1024 + o * 8 + (c & 7)] = f2bf(w[idx]);
}

// --------------- 256x256 bf16 MFMA GEMM, 8-phase counted-vmcnt ---------------
// 512 threads = 8 waves (2M x 4N), per-wave output 128x64 (acc 8x4). BK=64
// split into two 32-k slices; phase = one k-slice: 12 ds_read_b128 + 32 MFMA.
// LDS 128 KiB: [2 buf][2 slice] x (A[256][32] XOR-chunk 16KB + B[4][256][8] 16KB).
// Chunk c (4 GLLs) staged at phase c-3 into region last read at phase c-4;
// every phase entry: vmcnt(8) (2 chunks in flight, never drained until the end).
template <int ACT>
__global__ __launch_bounds__(512) void gemm8p(
    const ushort* __restrict__ A, const ushort* __restrict__ B,
    const float* __restrict__ bias, ushort* __restrict__ C,
    int M, int N, int K, float qscale, int qcols, int ntn) {
    __shared__ ushort AB[2][2][256 * 32];
    __shared__ ushort BB[2][2][4 * 256 * 8];

    // bijective XCD swizzle (m204)
    int nblk = gridDim.x;
    int q = nblk >> 3, rr = nblk & 7;
    int xcd = blockIdx.x & 7, sub = blockIdx.x >> 3;
    int wg = (xcd < rr ? xcd * (q + 1) : rr * (q + 1) + (xcd - rr) * q) + sub;
    int mt = wg / ntn, nt = wg - mt * ntn;
    int m0 = mt * 256, n0 = nt * 256;

    int tid = threadIdx.x;
    int w = tid >> 6, l = tid & 63;
    int wm = w >> 2;                    // 0..1: M half (128 rows)
    int wn = w & 3;                     // 0..3: N quarter (64 cols)
    int kg = l >> 4, c16 = l & 15;

    // staging source pointers (computed once; advanced per chunk)
    const ushort *aP0, *aP1, *bP0, *bP1;
    {
        int r0 = tid >> 2, ch0 = tid & 3;
        aP0 = A + (size_t)(m0 + r0) * K + ((ch0 ^ ((r0 >> 1) & 3)) << 3);
        int r1 = 128 + r0;
        aP1 = A + (size_t)(m0 + r1) * K + ((ch0 ^ ((r1 >> 1) & 3)) << 3);
        int kg0 = tid >> 8, col0 = tid & 255;
        bP0 = B + ((size_t)kg0 * N + n0 + col0) * 8;
        bP1 = B + ((size_t)(kg0 + 2) * N + n0 + col0) * 8;
    }
    const size_t bstep = (size_t)32 * N;   // 4 kgroups forward per 32-k chunk

#define STG(b_, s_) {                                                          \
        GLL(aP0, &AB[b_][s_][(w * 64) * 8]);        aP0 += 32;                 \
        GLL(aP1, &AB[b_][s_][(512 + w * 64) * 8]);  aP1 += 32;                 \
        GLL(bP0, &BB[b_][s_][(w * 64) * 8]);        bP0 += bstep;              \
        GLL(bP1, &BB[b_][s_][(512 + w * 64) * 8]);  bP1 += bstep; }

    f32x4 acc[8][4];
#pragma unroll
    for (int i = 0; i < 8; ++i)
#pragma unroll
        for (int j = 0; j < 4; ++j)
            acc[i][j] = (f32x4){0.f, 0.f, 0.f, 0.f};

#define PHC(b_, s_) {                                                          \
        const char* Ac = (const char*)AB[b_][s_];                              \
        const char* Bc = (const char*)BB[b_][s_];                              \
        bf16x8 af[8], bfv[4];                                                  \
        _Pragma("unroll")                                                      \
        for (int mi = 0; mi < 8; ++mi) {                                       \
            int row = wm * 128 + mi * 16 + c16;                                \
            af[mi] = *(const bf16x8*)(Ac + row * 64 + ((kg ^ ((row >> 1) & 3)) << 4)); \
        }                                                                      \
        _Pragma("unroll")                                                      \
        for (int ni = 0; ni < 4; ++ni) {                                       \
            int col = wn * 64 + ni * 16 + c16;                                 \
            bfv[ni] = *(const bf16x8*)(Bc + ((kg * 256 + col) << 4));          \
        }                                                                      \
        asm volatile("s_waitcnt lgkmcnt(0)" ::: "memory");                     \
        __builtin_amdgcn_sched_barrier(0);                                     \
        __builtin_amdgcn_s_setprio(1);                                         \
        _Pragma("unroll")                                                      \
        for (int mi = 0; mi < 8; ++mi)                                         \
            _Pragma("unroll")                                                  \
            for (int ni = 0; ni < 4; ++ni)                                     \
                acc[mi][ni] = __builtin_amdgcn_mfma_f32_16x16x32_bf16(         \
                    af[mi], bfv[ni], acc[mi][ni], 0, 0, 0);                    \
        __builtin_amdgcn_s_setprio(0); }

#define PH(vm_, pb_, ps_, dostg_, sb_, ss_) {                                  \
        asm volatile("s_waitcnt vmcnt(" #vm_ ")" ::: "memory");                \
        __builtin_amdgcn_s_barrier();                                          \
        __builtin_amdgcn_sched_barrier(0);                                     \
        if (dostg_) STG(sb_, ss_);                                             \
        PHC(pb_, ps_); }

    const int NCH = K >> 5;             // 32-k chunks: 24 (K=768) or 96 (K=3072)
    // prologue: chunks 0,1,2
    STG(0, 0); STG(0, 1); STG(1, 0);
    for (int p = 0; p + 4 < NCH; p += 4) {
        PH(8, 0, 0, 1, 1, 1);
        PH(8, 0, 1, 1, 0, 0);
        PH(8, 1, 0, 1, 0, 1);
        PH(8, 1, 1, 1, 1, 0);
    }
    // final 4 phases (chunks NCH-4..NCH-1); last stage is chunk NCH-1
    PH(8, 0, 0, 1, 1, 1);
    PH(8, 0, 1, 0, 0, 0);
    PH(4, 1, 0, 0, 0, 0);
    PH(0, 1, 1, 0, 0, 0);
#undef PH
#undef PHC
#undef STG

    // epilogue: row-outer, ni-inner -> each 128B line written contiguously
    int rhi = (l >> 4) * 4;
    float bvv[4], scl[4];
#pragma unroll
    for (int ni = 0; ni < 4; ++ni) {
        int col = n0 + wn * 64 + ni * 16 + c16;
        bvv[ni] = bias[col];
        scl[ni] = (col < qcols) ? qscale : 1.0f;
    }
#pragma unroll
    for (int mi = 0; mi < 8; ++mi) {
#pragma unroll
        for (int r = 0; r < 4; ++r) {
            int row = m0 + wm * 128 + mi * 16 + rhi + r;
#pragma unroll
            for (int ni = 0; ni < 4; ++ni) {
                int col = n0 + wn * 64 + ni * 16 + c16;
                float v = (acc[mi][ni][r] + bvv[ni]) * scl[ni];
                if (ACT == 1) v = 0.5f * v * (1.0f + erff(v * 0.70710678118654752f));
                C[(size_t)row * N + col] = f2bf(v);
            }
        }
    }
}

// ----------------------------- conv0: K-split implicit GEMM -----------------
__device__ __forceinline__ void conv0_stage(
    const ushort* __restrict__ hb, const ushort* __restrict__ W,
    ushort* Abuf, ushort* Bbuf, int tid, int m0, int kk, int kt) {
    int r0 = tid >> 2;
    int kgrp = (((tid & 3) ^ ((tid >> 3) & 3)) << 3);
    int w = tid >> 6;
    int r = m0 + r0;
    int b1 = r / 37, t1 = r - b1 * 37;
    int tok1 = b1 * SEQL + 2 * t1 + kk;
    int r2 = r + 64;
    int b2 = r2 / 37, t2 = r2 - b2 * 37;
    int tok2 = b2 * SEQL + 2 * t2 + kk;
    const ushort* ga0 = hb + (size_t)tok1 * DMODEL + kt * 32 + kgrp;
    const ushort* ga1 = hb + (size_t)tok2 * DMODEL + kt * 32 + kgrp;
    ushort* la = Abuf + (w * 64) * 8;
    GLL(ga0, la);
    GLL(ga1, la + 2048);
    const ushort* Bk = W + (size_t)kk * 98304;
    int g0 = tid >> 7, nn0 = tid & 127;
    int li1 = 256 + tid;
    int g1 = li1 >> 7, nn1 = li1 & 127;
    ushort* lb = Bbuf + (w * 64) * 8;
    GLL(Bk + ((size_t)(kt * 4 + g0) * 128 + nn0) * 8, lb);
    GLL(Bk + ((size_t)(kt * 4 + g1) * 128 + nn1) * 8, lb + 2048);
}

__global__ __launch_bounds__(256) void conv0_part(
    const ushort* __restrict__ hb, const ushort* __restrict__ W,
    float* __restrict__ part) {
    __shared__ ushort Abuf[2][128 * 32];
    __shared__ ushort Bbuf[2][32 * 128];
    int m0 = blockIdx.x * 128;
    int kk = blockIdx.y;
    int tid = threadIdx.x;
    int w = tid >> 6, l = tid & 63;
    int wm = w >> 1, wn = w & 1;
    f32x4 acc[4][4];
#pragma unroll
    for (int i = 0; i < 4; ++i)
#pragma unroll
        for (int j = 0; j < 4; ++j)
            acc[i][j] = (f32x4){0.f, 0.f, 0.f, 0.f};

    conv0_stage(hb, W, Abuf[0], Bbuf[0], tid, m0, kk, 0);
    __syncthreads();
    int cur = 0;
    for (int s = 0; s < 24; ++s) {
        if (s + 1 < 24)
            conv0_stage(hb, W, Abuf[cur ^ 1], Bbuf[cur ^ 1], tid, m0, kk, s + 1);
        const char* Ab = (const char*)&Abuf[cur][0];
        const char* Bb = (const char*)&Bbuf[cur][0];
        bf16x8 af[4], bfv[4];
        int kg = l >> 4, c16 = l & 15;
#pragma unroll
        for (int mi = 0; mi < 4; ++mi) {
            int row = wm * 64 + mi * 16 + c16;
            int byt = row * 64 + ((kg ^ ((row >> 1) & 3)) << 4);
            af[mi] = *(const bf16x8*)(Ab + byt);
        }
#pragma unroll
        for (int ni = 0; ni < 4; ++ni) {
            int col = wn * 64 + ni * 16 + c16;
            int byt = kg * 2048 + col * 16;
            bfv[ni] = *(const bf16x8*)(Bb + byt);
        }
#pragma unroll
        for (int mi = 0; mi < 4; ++mi)
#pragma unroll
            for (int ni = 0; ni < 4; ++ni)
                acc[mi][ni] = __builtin_amdgcn_mfma_f32_16x16x32_bf16(
                    af[mi], bfv[ni], acc[mi][ni], 0, 0, 0);
        __syncthreads();
        cur ^= 1;
    }

    int c16 = l & 15, rhi = (l >> 4) * 4;
    float* pk = part + (size_t)kk * (9472 * 128);
#pragma unroll
    for (int mi = 0; mi < 4; ++mi) {
#pragma unroll
        for (int r = 0; r < 4; ++r) {
            int row = m0 + wm * 64 + mi * 16 + rhi + r;
#pragma unroll
            for (int ni = 0; ni < 4; ++ni) {
                int col = wn * 64 + ni * 16 + c16;
                pk[(size_t)row * 128 + col] = acc[mi][ni][r];
            }
        }
    }
}

__global__ __launch_bounds__(256) void conv0_reduce(
    const float* __restrict__ part, const float* __restrict__ cb,
    const float* __restrict__ g, const float* __restrict__ bb,
    const float* __restrict__ bm, const float* __restrict__ bv,
    float* __restrict__ out) {
    int idx = blockIdx.x * 256 + threadIdx.x;
    if (idx >= 9472 * 128) return;
    int row = idx >> 7, col = idx & 127;
    float a = 0.f;
#pragma unroll
    for (int kk = 0; kk < 8; ++kk) a += part[(size_t)kk * (9472 * 128) + idx];
    float scl = g[col] * rsqrtf(bv[col] + 1e-5f);
    float y = (a + cb[col] - bm[col]) * scl + bb[col];
    int b = row / 37, t = row - b * 37;
    out[(size_t)b * (128 * 37) + col * 37 + t] = fmaxf(y, 0.f);
}

// ----------------------------- MFMA fused attention -------------------------
__global__ __launch_bounds__(256) void attn_mfma(
    const ushort* __restrict__ qkv, ushort* __restrict__ o) {
    __shared__ ushort Qs[96 * 64];
    __shared__ ushort Ks[96 * 64];
    __shared__ ushort Vs[12 * 64 * 8];
    __shared__ ushort Ps[96 * 128];
    __shared__ float pmax[2][96];
    __shared__ float psum[2][96];

    int b = blockIdx.x / NH, h = blockIdx.x % NH;
    const ushort* qp = qkv + (size_t)b * SEQL * 2304 + h * HD;
    const ushort* kp = qp + 768;
    const ushort* vp = qp + 1536;

    int tid = threadIdx.x;
    int w = tid >> 6, l = tid & 63;
    int wm = w >> 1, wn = w & 1;
    int kg = l >> 4, c16 = l & 15;

    {
        int lrow = l >> 3, chunk = l & 7;
#pragma unroll
        for (int p = 0; p < 3; ++p) {
            int seg = p * 4 + w;
            int row = seg * 8 + lrow;
            int rowg = row < SEQL ? row : SEQL - 1;
            int sch = chunk ^ (row & 7);
            GLL(qp + (size_t)rowg * 2304 + sch * 8, Qs + seg * 512);
            GLL(kp + (size_t)rowg * 2304 + sch * 8, Ks + seg * 512);
        }
    }
#pragma unroll
    for (int p = 0; p < 3; ++p) {
        int t = p * 256 + tid;
        int key = t >> 3, dg = t & 7;
        int keyg = key < SEQL ? key : SEQL - 1;
        us8 vv = *(const us8*)(vp + (size_t)keyg * 2304 + dg * 8);
        int base = (key >> 3) * 512 + dg * 64 + (key & 7);
#pragma unroll
        for (int j = 0; j < 8; ++j) Vs[base + j * 8] = vv[j];
    }
    __syncthreads();

    f32x4 sacc[3][3];
#pragma unroll
    for (int i = 0; i < 3; ++i)
#pragma unroll
        for (int j = 0; j < 3; ++j) sacc[i][j] = (f32x4){0.f, 0.f, 0.f, 0.f};
    {
        const char* Qc = (const char*)Qs;
        const char* Kc = (const char*)Ks;
#pragma unroll
        for (int kt = 0; kt < 2; ++kt) {
            bf16x8 qa[3], ka[3];
#pragma unroll
            for (int mi = 0; mi < 3; ++mi) {
                int row = wm * 48 + mi * 16 + c16;
                qa[mi] = *(const bf16x8*)(Qc + row * 128 + (((kt * 4 + kg) ^ (row & 7)) << 4));
            }
#pragma unroll
            for (int ni = 0; ni < 3; ++ni) {
                int col = wn * 48 + ni * 16 + c16;
                ka[ni] = *(const bf16x8*)(Kc + col * 128 + (((kt * 4 + kg) ^ (col & 7)) << 4));
            }
#pragma unroll
            for (int mi = 0; mi < 3; ++mi)
#pragma unroll
                for (int ni = 0; ni < 3; ++ni)
                    sacc[mi][ni] = __builtin_amdgcn_mfma_f32_16x16x32_bf16(
                        qa[mi], ka[ni], sacc[mi][ni], 0, 0, 0);
        }
    }

#pragma unroll
    for (int mi = 0; mi < 3; ++mi) {
#pragma unroll
        for (int r = 0; r < 4; ++r) {
            float m = -3e30f;
#pragma unroll
            for (int ni = 0; ni < 3; ++ni) {
                int col = wn * 48 + ni * 16 + c16;
                float v = sacc[mi][ni][r];
                if (col >= SEQL) { v = -3e30f; sacc[mi][ni][r] = v; }
                m = fmaxf(m, v);
            }
#pragma unroll
            for (int off = 1; off < 16; off <<= 1) m = fmaxf(m, __shfl_xor(m, off, 64));
            if (c16 == 0) pmax[wn][wm * 48 + mi * 16 + kg * 4 + r] = m;
        }
    }
    __syncthreads();
#pragma unroll
    for (int mi = 0; mi < 3; ++mi) {
#pragma unroll
        for (int r = 0; r < 4; ++r) {
            int row = wm * 48 + mi * 16 + kg * 4 + r;
            float m = fmaxf(pmax[0][row], pmax[1][row]);
            float s = 0.f;
#pragma unroll
            for (int ni = 0; ni < 3; ++ni) {
                float pv = __expf(sacc[mi][ni][r] - m);
                sacc[mi][ni][r] = pv;
                s += pv;
            }
#pragma unroll
            for (int off = 1; off < 16; off <<= 1) s += __shfl_xor(s, off, 64);
            if (c16 == 0) psum[wn][row] = s;
#pragma unroll
            for (int ni = 0; ni < 3; ++ni) {
                int col = wn * 48 + ni * 16 + c16;
                Ps[row * 128 + ((((col >> 3) ^ (row & 7))) << 3) + (col & 7)] =
                    f2bf(sacc[mi][ni][r]);
            }
        }
    }
    __syncthreads();

    f32x4 oacc[3][2];
#pragma unroll
    for (int i = 0; i < 3; ++i)
#pragma unroll
        for (int j = 0; j < 2; ++j) oacc[i][j] = (f32x4){0.f, 0.f, 0.f, 0.f};
    {
        const char* Pc = (const char*)Ps;
        const char* Vc = (const char*)Vs;
#pragma unroll
        for (int ks = 0; ks < 3; ++ks) {
            bf16x8 pa[3], va[2];
#pragma unroll
            for (int mi = 0; mi < 3; ++mi) {
                int row = wm * 48 + mi * 16 + c16;
                pa[mi] = *(const bf16x8*)(Pc + row * 256 + (((ks * 4 + kg) ^ (row & 7)) << 4));
            }
#pragma unroll
            for (int ni = 0; ni < 2; ++ni) {
                int col = wn * 32 + ni * 16 + c16;
                va[ni] = *(const bf16x8*)(Vc + (ks * 4 + kg) * 1024 + col * 16);
            }
#pragma unroll
            for (int mi = 0; mi < 3; ++mi)
#pragma unroll
                for (int ni = 0; ni < 2; ++ni)
                    oacc[mi][ni] = __builtin_amdgcn_mfma_f32_16x16x32_bf16(
                        pa[mi], va[ni], oacc[mi][ni], 0, 0, 0);
        }
    }

#pragma unroll
    for (int mi = 0; mi < 3; ++mi) {
#pragma unroll
        for (int r = 0; r < 4; ++r) {
            int row = wm * 48 + mi * 16 + kg * 4 + r;
            if (row < SEQL) {
                float inv = 1.0f / (psum[0][row] + psum[1][row]);
                size_t obase = (size_t)(b * SEQL + row) * DMODEL + h * HD;
#pragma unroll
                for (int ni = 0; ni < 2; ++ni) {
                    int col = wn * 32 + ni * 16 + c16;
                    o[obase + col] = f2bf(oacc[mi][ni][r] * inv);
                }
            }
        }
    }
}

// ----------------------------- small conv tail -----------------------------
__global__ void conv1_kernel(const float* __restrict__ x, const float* __restrict__ w,
                             const float* __restrict__ cb, const float* __restrict__ g,
                             const float* __restrict__ bb, const float* __restrict__ bm,
                             const float* __restrict__ bv, float* __restrict__ out) {
    int idx = blockIdx.x * blockDim.x + threadIdx.x;
    if (idx >= BATCH * 64 * 14) return;
    int t = idx % 14, o = (idx / 14) % 64, b = idx / (14 * 64);
    float acc = cb[o];
    const float* wo = w + (long)o * 128 * 8;
    const float* xb = x + (long)b * 128 * 35;
    for (int c = 0; c < 128; ++c) {
#pragma unroll
        for (int kk = 0; kk < 8; ++kk)
            acc += xb[c * 35 + 2 * t + kk] * wo[c * 8 + kk];
    }
    float y = (acc - bm[o]) * g[o] * rsqrtf(bv[o] + 1e-5f) + bb[o];
    out[idx] = fmaxf(y, 0.0f);
}

__global__ void conv2_kernel(const float* __restrict__ x, const float* __restrict__ w,
                             const float* __restrict__ cb, const float* __restrict__ g,
                             const float* __restrict__ bb, const float* __restrict__ bm,
                             const float* __restrict__ bv, float* __restrict__ out) {
    int idx = blockIdx.x * blockDim.x + threadIdx.x;
    if (idx >= BATCH * 32 * 5) return;
    int t = idx % 5, o = (idx / 5) % 32, b = idx / (5 * 32);
    float acc = cb[o];
    const float* wo = w + (long)o * 64 * 3;
    const float* xb = x + (long)b * 64 * 12;
    for (int c = 0; c < 64; ++c) {
#pragma unroll
        for (int kk = 0; kk < 3; ++kk)
            acc += xb[c * 12 + 2 * t + kk] * wo[c * 3 + kk];
    }
    float y = (acc - bm[o]) * g[o] * rsqrtf(bv[o] + 1e-5f) + bb[o];
    out[idx] = fmaxf(y, 0.0f);
}

__global__ void pool_kernel(const float* __restrict__ in, float* __restrict__ out,
                            int C, int Tin) {
    int Tout = Tin - 2;
    int idx = blockIdx.x * blockDim.x + threadIdx.x;
    if (idx >= BATCH * C * Tout) return;
    int t = idx % Tout;
    int co = idx / Tout;
    const float* p = in + (long)co * Tin + t;
    out[idx] = fmaxf(fmaxf(p[0], p[1]), p[2]);
}

__global__ __launch_bounds__(64) void head_kernel(
    const float* __restrict__ x, const float* __restrict__ w1,
    const float* __restrict__ b1, const float* __restrict__ w2,
    const float* __restrict__ b2, float* __restrict__ out) {
    int b = blockIdx.x;
    int j = threadIdx.x;
    float y = 0.f;
    if (j < 32) {
        float acc = b1[j];
        const float* xb = x + b * 96;
        for (int i = 0; i < 96; ++i) acc += xb[i] * w1[j * 96 + i];
        y = fmaxf(acc, 0.0f) * w2[j];
    }
#pragma unroll
    for (int o = 32; o > 0; o >>= 1) y += __shfl_down(y, o, 64);
    if (j == 0) out[b] = 1.0f / (1.0f + expf(-(y + b2[0])));
}

// ----------------------------- launch -----------------------------
extern "C" void kernel_launch(void* const* d_in, const int* in_sizes, int n_in,
                              void* d_out, int out_size, void* d_ws, size_t ws_size,
                              hipStream_t stream) {
    const int*   ids  = (const int*)d_in[0];
    const float* wemb = (const float*)d_in[1];
    const float* pemb = (const float*)d_in[2];
    const float* elng = (const float*)d_in[3];
    const float* elnb = (const float*)d_in[4];
    const float* wq = (const float*)d_in[5];
    const float* bq = (const float*)d_in[6];
    const float* wk = (const float*)d_in[7];
    const float* bk = (const float*)d_in[8];
    const float* wv = (const float*)d_in[9];
    const float* bv = (const float*)d_in[10];
    const float* wo = (const float*)d_in[11];
    const float* bo = (const float*)d_in[12];
    const float* ln1g = (const float*)d_in[13];
    const float* ln1b = (const float*)d_in[14];
    const float* w1 = (const float*)d_in[15];
    const float* b1 = (const float*)d_in[16];
    const float* w2 = (const float*)d_in[17];
    const float* b2 = (const float*)d_in[18];
    const float* ln2g = (const float*)d_in[19];
    const float* ln2b = (const float*)d_in[20];
    const float* c0w = (const float*)d_in[21];
    const float* c0b = (const float*)d_in[22];
    const float* g0 = (const float*)d_in[23];
    const float* bb0 = (const float*)d_in[24];
    const float* m0 = (const float*)d_in[25];
    const float* v0 = (const float*)d_in[26];
    const float* c1w = (const float*)d_in[27];
    const float* c1b = (const float*)d_in[28];
    const float* g1 = (const float*)d_in[29];
    const float* bb1 = (const float*)d_in[30];
    const float* m1 = (const float*)d_in[31];
    const float* v1 = (const float*)d_in[32];
    const float* c2w = (const float*)d_in[33];
    const float* c2b = (const float*)d_in[34];
    const float* g2 = (const float*)d_in[35];
    const float* bb2 = (const float*)d_in[36];
    const float* m2 = (const float*)d_in[37];
    const float* v2 = (const float*)d_in[38];
    const float* d1w = (const float*)d_in[39];
    const float* d1b = (const float*)d_in[40];
    const float* d2w = (const float*)d_in[41];
    const float* d2b = (const float*)d_in[42];
    (void)in_sizes; (void)n_in; (void)out_size; (void)ws_size;

    const size_t SZ = (size_t)NTOK * DMODEL;
    char* p = (char*)d_ws;
    ushort* hb   = (ushort*)p; p += SZ * 2;
    ushort* qkvb = (ushort*)p; p += (size_t)NTOK * 2304 * 2;
    ushort* ob   = (ushort*)p; p += SZ * 2;
    ushort* rb   = (ushort*)p; p += SZ * 2;
    ushort* qkvw = (ushort*)p; p += (size_t)DMODEL * 2304 * 2;
    ushort* wob  = (ushort*)p; p += (size_t)DMODEL * DMODEL * 2;
    ushort* w1b  = (ushort*)p; p += (size_t)DMODEL * FFDIM * 2;
    ushort* w2b  = (ushort*)p; p += (size_t)FFDIM * DMODEL * 2;
    float*  cbias= (float*)p;  p += 2304 * 4;
    ushort* wc0  = (ushort*)p; p += (size_t)8 * 96 * 128 * 8 * 2;
    float* c0 = (float*)p;  p += (size_t)BATCH * 128 * 37 * 4;
    float* p0 = (float*)p;  p += (size_t)BATCH * 128 * 35 * 4;
    float* c1 = (float*)p;  p += (size_t)BATCH * 64 * 14 * 4;
    float* p1 = (float*)p;  p += (size_t)BATCH * 64 * 12 * 4;
    float* c2 = (float*)p;  p += (size_t)BATCH * 32 * 5 * 4;
    float* p2 = (float*)p;  p += (size_t)BATCH * 32 * 3 * 4;
    ushort* ff = (ushort*)p;
    float* part = (float*)qkvb;   // conv0 partials reuse dead qkv buffer

    embed_ln_kernel<<<NTOK, 256, 0, stream>>>(ids, wemb, pemb, elng, elnb, hb);
    convw_c0<<<(128 * 768 * 8 + 255) / 256, 256, 0, stream>>>(c0w, wc0);

    const int NWG_QKV = (NTOK / 256) * (2304 / 256);   // 81*9 = 729
    const int NWG_WO  = (NTOK / 256) * (768 / 256);    // 81*3 = 243
    const int NWG_F1  = (NTOK / 256) * (FFDIM / 256);  // 81*12 = 972
    const int NWG_F2  = (NTOK / 256) * (768 / 256);    // 243

    for (int l = 0; l < NLAYER; ++l) {
        convw_layer<<<4096, 256, 0, stream>>>(
            wq + (size_t)l * SQ1, wk + (size_t)l * SQ1, wv + (size_t)l * SQ1,
            wo + (size_t)l * SQ1, w1 + (size_t)l * SQ2, w2 + (size_t)l * SQ2,
            bq + (size_t)l * DMODEL, bk + (size_t)l * DMODEL, bv + (size_t)l * DMODEL,
            qkvw, wob, w1b, w2b, cbias);

        gemm8p<0><<<NWG_QKV, 512, 0, stream>>>(hb, qkvw, cbias, qkvb,
                                               NTOK, 2304, DMODEL, 0.125f, 768, 9);
        attn_mfma<<<BATCH * NH, 256, 0, stream>>>(qkvb, ob);
        gemm8p<0><<<NWG_WO, 512, 0, stream>>>(ob, wob, bo + (size_t)l * DMODEL, rb,
                                              NTOK, DMODEL, DMODEL, 1.0f, 0, 3);
        add_ln_kernel<<<NTOK, 192, 0, stream>>>(hb, rb, ln1g + (size_t)l * DMODEL,
                                                ln1b + (size_t)l * DMODEL);
        gemm8p<1><<<NWG_F1, 512, 0, stream>>>(hb, w1b, b1 + (size_t)l * FFDIM, ff,
                                              NTOK, FFDIM, DMODEL, 1.0f, 0, 12);
        gemm8p<0><<<NWG_F2, 512, 0, stream>>>(ff, w2b, b2 + (size_t)l * DMODEL, rb,
                                              NTOK, DMODEL, FFDIM, 1.0f, 0, 3);
        add_ln_kernel<<<NTOK, 192, 0, stream>>>(hb, rb, ln2g + (size_t)l * DMODEL,
                                                ln2b + (size_t)l * DMODEL);
    }

    // CNN / MLP head
    {
        conv0_part<<<dim3(74, 8), 256, 0, stream>>>(hb, wc0, part);
        conv0_reduce<<<(9472 * 128 + 255) / 256, 256, 0, stream>>>(part, c0b, g0, bb0, m0, v0, c0);
        int n = BATCH * 128 * 35;
        pool_kernel<<<(n + 255) / 256, 256, 0, stream>>>(c0, p0, 128, 37);
        n = BATCH * 64 * 14;
        conv1_kernel<<<(n + 255) / 256, 256, 0, stream>>>(p0, c1w, c1b, g1, bb1, m1, v1, c1);
        n = BATCH * 64 * 12;
        pool_kernel<<<(n + 255) / 256, 256, 0, stream>>>(c1, p1, 64, 14);
        n = BATCH * 32 * 5;
        conv2_kernel<<<(n + 255) / 256, 256, 0, stream>>>(p1, c2w, c2b, g2, bb2, m2, v2, c2);
        n = BATCH * 32 * 3;
        pool_kernel<<<(n + 255) / 256, 256, 0, stream>>>(c2, p2, 32, 5);
        head_kernel<<<BATCH, 64, 0, stream>>>(p2, d1w, d1b, d2w, d2b, (float*)d_out);
    }
}

// Round 14
// 6324.149 us; speedup vs baseline: 1.0062x; 1.0062x over previous
//
#include <hip/hip_runtime.h>
#include <hip/hip_bf16.h>

#define DMODEL 768
#define HD     64
#define NH     12
#define SEQL   81
#define BATCH  256
#define NTOK   (BATCH*SEQL)   /* 20736 */
#define FFDIM  3072
#define NLAYER 12

typedef __bf16 bf16x8 __attribute__((ext_vector_type(8)));
typedef float  f32x4  __attribute__((ext_vector_type(4)));
typedef unsigned short us8 __attribute__((ext_vector_type(8)));

__device__ __forceinline__ float bf2f(ushort u) {
    union { float f; unsigned u; } c; c.u = ((unsigned)u) << 16; return c.f;
}
__device__ __forceinline__ ushort f2bf(float f) {
    union { float f; unsigned u; } c; c.f = f;
    unsigned x = c.u;
    unsigned r = (x + 0x7fffu + ((x >> 16) & 1u)) >> 16;
    return (ushort)r;
}

#define GLL(gptr, lptr) __builtin_amdgcn_global_load_lds( \
    (const __attribute__((address_space(1))) void*)(gptr), \
    (__attribute__((address_space(3))) void*)(lptr), 16, 0, 0)

// ----------------------------- reductions -----------------------------
__device__ __forceinline__ float wave_sum(float v) {
#pragma unroll
    for (int o = 32; o > 0; o >>= 1) v += __shfl_down(v, o, 64);
    return v;
}

__device__ __forceinline__ void block_sum2_w4(float& a, float& b, float* red) {
    a = wave_sum(a); b = wave_sum(b);
    int lane = threadIdx.x & 63, wid = threadIdx.x >> 6;
    if (lane == 0) { red[wid] = a; red[4 + wid] = b; }
    __syncthreads();
    a = red[0] + red[1] + red[2] + red[3];
    b = red[4] + red[5] + red[6] + red[7];
    __syncthreads();
}
__device__ __forceinline__ void block_sum2_w3(float& a, float& b, float* red) {
    a = wave_sum(a); b = wave_sum(b);
    int lane = threadIdx.x & 63, wid = threadIdx.x >> 6;
    if (lane == 0) { red[wid] = a; red[3 + wid] = b; }
    __syncthreads();
    a = red[0] + red[1] + red[2];
    b = red[3] + red[4] + red[5];
    __syncthreads();
}

// ----------------------------- embedding + LN (bf16 out) --------------------
__global__ __launch_bounds__(256) void embed_ln_kernel(
    const int* __restrict__ ids, const float* __restrict__ wemb,
    const float* __restrict__ pemb, const float* __restrict__ g,
    const float* __restrict__ b, ushort* __restrict__ outb) {
    __shared__ float red[8];
    int tok = blockIdx.x;
    int s = tok % SEQL;
    long base = (long)ids[tok] * DMODEL;
    float vals[3];
    float sum = 0.f, sq = 0.f;
#pragma unroll
    for (int i = 0; i < 3; ++i) {
        int c = threadIdx.x + i * 256;
        float x = wemb[base + c] + pemb[s * DMODEL + c];
        vals[i] = x; sum += x; sq += x * x;
    }
    block_sum2_w4(sum, sq, red);
    float mean = sum * (1.0f / DMODEL);
    float inv = rsqrtf(sq * (1.0f / DMODEL) - mean * mean + 1e-5f);
#pragma unroll
    for (int i = 0; i < 3; ++i) {
        int c = threadIdx.x + i * 256;
        float y = (vals[i] - mean) * inv * g[c] + b[c];
        outb[(size_t)tok * DMODEL + c] = f2bf(y);
    }
}

// hb = bf16(LN(hb + r)); bf16 residual stream. 192 threads, ushort4.
__global__ __launch_bounds__(192) void add_ln_kernel(
    ushort* __restrict__ hb, const ushort* __restrict__ r,
    const float* __restrict__ g, const float* __restrict__ b) {
    __shared__ float red[6];
    size_t base = (size_t)blockIdx.x * DMODEL;
    int c = threadIdx.x * 4;
    ushort4 hv = *(const ushort4*)(hb + base + c);
    ushort4 rv = *(const ushort4*)(r + base + c);
    float vals[4];
    vals[0] = bf2f(hv.x) + bf2f(rv.x); vals[1] = bf2f(hv.y) + bf2f(rv.y);
    vals[2] = bf2f(hv.z) + bf2f(rv.z); vals[3] = bf2f(hv.w) + bf2f(rv.w);
    float sum = 0.f, sq = 0.f;
#pragma unroll
    for (int i = 0; i < 4; ++i) { sum += vals[i]; sq += vals[i] * vals[i]; }
    block_sum2_w3(sum, sq, red);
    float mean = sum * (1.0f / DMODEL);
    float inv = rsqrtf(sq * (1.0f / DMODEL) - mean * mean + 1e-5f);
    float4 gv = *(const float4*)(g + c);
    float4 bv = *(const float4*)(b + c);
    ushort4 ov;
    ov.x = f2bf((vals[0] - mean) * inv * gv.x + bv.x);
    ov.y = f2bf((vals[1] - mean) * inv * gv.y + bv.y);
    ov.z = f2bf((vals[2] - mean) * inv * gv.z + bv.z);
    ov.w = f2bf((vals[3] - mean) * inv * gv.w + bv.w);
    *(ushort4*)(hb + base + c) = ov;
}

// ----------------------------- weight conversion (per layer, fused) -----------
#define SQ1 589824                 /* 768*768 */
#define SQ2 2359296                /* 768*3072 */
#define CW_TOTAL (4*SQ1 + 2*SQ2 + 2304)
__global__ __launch_bounds__(256) void convw_layer(
    const float* __restrict__ wq, const float* __restrict__ wk,
    const float* __restrict__ wv, const float* __restrict__ wo,
    const float* __restrict__ w1, const float* __restrict__ w2,
    const float* __restrict__ bq, const float* __restrict__ bk,
    const float* __restrict__ bvp,
    ushort* __restrict__ qkvw, ushort* __restrict__ wob,
    ushort* __restrict__ w1b, ushort* __restrict__ w2b,
    float* __restrict__ cbias) {
    for (int i = blockIdx.x * 256 + threadIdx.x; i < CW_TOTAL; i += gridDim.x * 256) {
        if (i < 3 * SQ1) {
            int widx = i / SQ1, j = i - widx * SQ1;
            const float* src = widx == 0 ? wq : (widx == 1 ? wk : wv);
            int k = j / 768, n = j - k * 768;
            qkvw[(size_t)(k >> 3) * 2304 * 8 + (widx * 768 + n) * 8 + (k & 7)] = f2bf(src[j]);
        } else if (i < 4 * SQ1) {
            int j = i - 3 * SQ1;
            int k = j / 768, n = j - k * 768;
            wob[(size_t)(k >> 3) * 768 * 8 + n * 8 + (k & 7)] = f2bf(wo[j]);
        } else if (i < 4 * SQ1 + SQ2) {
            int j = i - 4 * SQ1;
            int k = j / 3072, n = j - k * 3072;
            w1b[(size_t)(k >> 3) * 3072 * 8 + n * 8 + (k & 7)] = f2bf(w1[j]);
        } else if (i < 4 * SQ1 + 2 * SQ2) {
            int j = i - 4 * SQ1 - SQ2;
            int k = j / 768, n = j - k * 768;
            w2b[(size_t)(k >> 3) * 768 * 8 + n * 8 + (k & 7)] = f2bf(w2[j]);
        } else {
            int j = i - 4 * SQ1 - 2 * SQ2;
            cbias[j] = j < 768 ? bq[j] : (j < 1536 ? bk[j - 768] : bvp[j - 1536]);
        }
    }
}

// conv0 weights: w[o][c][kk] fp32 -> dst[kk][(c>>3)*1024 + o*8 + (c&7)] bf16
__global__ __launch_bounds__(256) void convw_c0(
    const float* __restrict__ w, ushort* __restrict__ dst) {
    int idx = blockIdx.x * 256 + threadIdx.x;
    if (idx >= 128 * 768 * 8) return;
    int o = idx / 6144, rem = idx - o * 6144, c = rem >> 3, kk = rem & 7;
    dst[(size_t)kk * 98304 + (size_t)(c >> 3) * 1024 + o * 8 + (c & 7)] = f2bf(w[idx]);
}

// ----------------------------- 256x128 bf16 MFMA GEMM (r9 champion) ----------
// 512 threads = 8 waves (4M x 2N), per-wave output 64x64 (acc 4x4). BK=32.
// LDS 48 KiB -> 3 blocks/CU. A row-major [256][32] with XOR key (row>>1)&3
// (2-way free); B [kg(4)][col(128)][8] (2-way free). Counted vmcnt(3).
__device__ __forceinline__ void g_stage2(
    const ushort*& a0, const ushort*& a1, const ushort*& b0,
    ushort* Abuf, ushort* Bbuf, int w, size_t bstep) {
    GLL(a0, Abuf + (size_t)(w * 64) * 8);          a0 += 32;
    GLL(a1, Abuf + (size_t)(512 + w * 64) * 8);    a1 += 32;
    GLL(b0, Bbuf + (size_t)(w * 64) * 8);          b0 += bstep;
}

#define GEMM_COMPUTE(Ab_, Bb_)                                                 \
    {                                                                          \
        const char* Ab = (const char*)(Ab_);                                   \
        const char* Bb = (const char*)(Bb_);                                   \
        bf16x8 af[4], bfv[4];                                                  \
        _Pragma("unroll")                                                      \
        for (int mi = 0; mi < 4; ++mi) {                                       \
            int row = wm4 * 64 + mi * 16 + c16;                                \
            int byt = row * 64 + ((kg ^ ((row >> 1) & 3)) << 4);               \
            af[mi] = *(const bf16x8*)(Ab + byt);                               \
        }                                                                      \
        _Pragma("unroll")                                                      \
        for (int ni = 0; ni < 4; ++ni) {                                       \
            int col = wn2 * 64 + ni * 16 + c16;                                \
            bfv[ni] = *(const bf16x8*)(Bb + ((size_t)kg * 128 + col) * 16);    \
        }                                                                      \
        __builtin_amdgcn_s_setprio(1);                                         \
        _Pragma("unroll")                                                      \
        for (int mi = 0; mi < 4; ++mi)                                         \
            _Pragma("unroll")                                                  \
            for (int ni = 0; ni < 4; ++ni)                                     \
                acc[mi][ni] = __builtin_amdgcn_mfma_f32_16x16x32_bf16(         \
                    af[mi], bfv[ni], acc[mi][ni], 0, 0, 0);                    \
        __builtin_amdgcn_s_setprio(0);                                         \
    }

template <int ACT>
__global__ __launch_bounds__(512) void gemm_t(
    const ushort* __restrict__ A, const ushort* __restrict__ B,
    const float* __restrict__ bias, ushort* __restrict__ C,
    int M, int N, int K, float qscale, int qcols, int ntn) {
    __shared__ ushort Abuf[2][256 * 32];
    __shared__ ushort Bbuf[2][4 * 128 * 8];

    // bijective XCD swizzle (m204)
    int nblk = gridDim.x;
    int q = nblk >> 3, rr = nblk & 7;
    int xcd = blockIdx.x & 7, sub = blockIdx.x >> 3;
    int wg = (xcd < rr ? xcd * (q + 1) : rr * (q + 1) + (xcd - rr) * q) + sub;
    int mt = wg / ntn, nt = wg - mt * ntn;
    int m0 = mt * 256, n0 = nt * 128;

    int tid = threadIdx.x;
    int w = tid >> 6, l = tid & 63;
    int wm4 = w >> 1;                   // 0..3: M group of 64 rows
    int wn2 = w & 1;                    // 0..1: N group of 64 cols
    int kg = l >> 4, c16 = l & 15;

    // per-thread staging source pointers (computed once)
    const ushort *aP0, *aP1, *bP;
    {
        int r0 = tid >> 2, ch0 = tid & 3;
        aP0 = A + (size_t)(m0 + r0) * K + ((ch0 ^ ((r0 >> 1) & 3)) << 3);
        int ci1 = 512 + tid;
        int r1 = ci1 >> 2, ch1 = ci1 & 3;
        aP1 = A + (size_t)(m0 + r1) * K + ((ch1 ^ ((r1 >> 1) & 3)) << 3);
        int gg = tid >> 7, n = tid & 127;
        bP = B + ((size_t)gg * N + n0 + n) * 8;
    }
    const size_t bstep = (size_t)32 * N;

    f32x4 acc[4][4];
#pragma unroll
    for (int i = 0; i < 4; ++i)
#pragma unroll
        for (int j = 0; j < 4; ++j)
            acc[i][j] = (f32x4){0.f, 0.f, 0.f, 0.f};

    const int KT = K >> 5;              // always even (24 or 96)
    g_stage2(aP0, aP1, bP, Abuf[0], Bbuf[0], w, bstep);
    for (int t = 0; t < KT; t += 2) {
        g_stage2(aP0, aP1, bP, Abuf[1], Bbuf[1], w, bstep);
        asm volatile("s_waitcnt vmcnt(3)" ::: "memory");
        __builtin_amdgcn_s_barrier();
        __builtin_amdgcn_sched_barrier(0);
        GEMM_COMPUTE(Abuf[0], Bbuf[0]);
        __builtin_amdgcn_s_barrier();
        if (t + 2 < KT) {
            g_stage2(aP0, aP1, bP, Abuf[0], Bbuf[0], w, bstep);
            asm volatile("s_waitcnt vmcnt(3)" ::: "memory");
        } else {
            asm volatile("s_waitcnt vmcnt(0)" ::: "memory");
        }
        __builtin_amdgcn_s_barrier();
        __builtin_amdgcn_sched_barrier(0);
        GEMM_COMPUTE(Abuf[1], Bbuf[1]);
        __builtin_amdgcn_s_barrier();
    }

    // epilogue: row-outer, ni-inner -> each 128B line written contiguously
    int rhi = (l >> 4) * 4;
    float bvv[4], scl[4];
#pragma unroll
    for (int ni = 0; ni < 4; ++ni) {
        int col = n0 + wn2 * 64 + ni * 16 + c16;
        bvv[ni] = bias[col];
        scl[ni] = (col < qcols) ? qscale : 1.0f;
    }
#pragma unroll
    for (int mi = 0; mi < 4; ++mi) {
#pragma unroll
        for (int r = 0; r < 4; ++r) {
            int row = m0 + wm4 * 64 + mi * 16 + rhi + r;
#pragma unroll
            for (int ni = 0; ni < 4; ++ni) {
                int col = n0 + wn2 * 64 + ni * 16 + c16;
                float v = (acc[mi][ni][r] + bvv[ni]) * scl[ni];
                if (ACT == 1) v = 0.5f * v * (1.0f + erff(v * 0.70710678118654752f));
                C[(size_t)row * N + col] = f2bf(v);
            }
        }
    }
}

// ------------------- 128x128 variant (4 waves) for N=768 GEMMs ---------------
// Same pipeline; grid doubles M-tiles -> full CU coverage for WO/F2 (972 blocks).
__device__ __forceinline__ void g_stage_s(
    const ushort*& a0, const ushort*& a1, const ushort*& b0, const ushort*& b1,
    ushort* Abuf, ushort* Bbuf, int w, size_t bstep) {
    GLL(a0, Abuf + (size_t)(w * 64) * 8);         a0 += 32;
    GLL(a1, Abuf + (size_t)(256 + w * 64) * 8);   a1 += 32;
    GLL(b0, Bbuf + (size_t)(w * 64) * 8);         b0 += bstep;
    GLL(b1, Bbuf + (size_t)(256 + w * 64) * 8);   b1 += bstep;
}

#define GEMM_COMPUTE_S(Ab_, Bb_)                                               \
    {                                                                          \
        const char* Ab = (const char*)(Ab_);                                   \
        const char* Bb = (const char*)(Bb_);                                   \
        bf16x8 af[4], bfv[4];                                                  \
        _Pragma("unroll")                                                      \
        for (int mi = 0; mi < 4; ++mi) {                                       \
            int row = wm2 * 64 + mi * 16 + c16;                                \
            int byt = row * 64 + ((kg ^ ((row >> 1) & 3)) << 4);               \
            af[mi] = *(const bf16x8*)(Ab + byt);                               \
        }                                                                      \
        _Pragma("unroll")                                                      \
        for (int ni = 0; ni < 4; ++ni) {                                       \
            int col = wn2 * 64 + ni * 16 + c16;                                \
            bfv[ni] = *(const bf16x8*)(Bb + ((size_t)kg * 128 + col) * 16);    \
        }                                                                      \
        __builtin_amdgcn_s_setprio(1);                                         \
        _Pragma("unroll")                                                      \
        for (int mi = 0; mi < 4; ++mi)                                         \
            _Pragma("unroll")                                                  \
            for (int ni = 0; ni < 4; ++ni)                                     \
                acc[mi][ni] = __builtin_amdgcn_mfma_f32_16x16x32_bf16(         \
                    af[mi], bfv[ni], acc[mi][ni], 0, 0, 0);                    \
        __builtin_amdgcn_s_setprio(0);                                         \
    }

template <int ACT>
__global__ __launch_bounds__(256) void gemm_s(
    const ushort* __restrict__ A, const ushort* __restrict__ B,
    const float* __restrict__ bias, ushort* __restrict__ C,
    int M, int N, int K, float qscale, int qcols, int ntn) {
    __shared__ ushort Abuf[2][128 * 32];
    __shared__ ushort Bbuf[2][4 * 128 * 8];

    int nblk = gridDim.x;
    int q = nblk >> 3, rr = nblk & 7;
    int xcd = blockIdx.x & 7, sub = blockIdx.x >> 3;
    int wg = (xcd < rr ? xcd * (q + 1) : rr * (q + 1) + (xcd - rr) * q) + sub;
    int mt = wg / ntn, nt = wg - mt * ntn;
    int m0 = mt * 128, n0 = nt * 128;

    int tid = threadIdx.x;
    int w = tid >> 6, l = tid & 63;
    int wm2 = w >> 1;                   // 0..1: M group of 64 rows
    int wn2 = w & 1;                    // 0..1: N group of 64 cols
    int kg = l >> 4, c16 = l & 15;

    const ushort *aP0, *aP1, *bP0, *bP1;
    {
        int r0 = tid >> 2, ch0 = tid & 3;
        aP0 = A + (size_t)(m0 + r0) * K + ((ch0 ^ ((r0 >> 1) & 3)) << 3);
        int ci1 = 256 + tid;
        int r1 = ci1 >> 2, ch1 = ci1 & 3;
        aP1 = A + (size_t)(m0 + r1) * K + ((ch1 ^ ((r1 >> 1) & 3)) << 3);
        int g0 = tid >> 7, n_ = tid & 127;
        bP0 = B + ((size_t)g0 * N + n0 + n_) * 8;
        int gi1 = 256 + tid;
        int g1 = gi1 >> 7, n1 = gi1 & 127;
        bP1 = B + ((size_t)g1 * N + n0 + n1) * 8;
    }
    const size_t bstep = (size_t)32 * N;

    f32x4 acc[4][4];
#pragma unroll
    for (int i = 0; i < 4; ++i)
#pragma unroll
        for (int j = 0; j < 4; ++j)
            acc[i][j] = (f32x4){0.f, 0.f, 0.f, 0.f};

    const int KT = K >> 5;
    g_stage_s(aP0, aP1, bP0, bP1, Abuf[0], Bbuf[0], w, bstep);
    for (int t = 0; t < KT; t += 2) {
        g_stage_s(aP0, aP1, bP0, bP1, Abuf[1], Bbuf[1], w, bstep);
        asm volatile("s_waitcnt vmcnt(4)" ::: "memory");
        __builtin_amdgcn_s_barrier();
        __builtin_amdgcn_sched_barrier(0);
        GEMM_COMPUTE_S(Abuf[0], Bbuf[0]);
        __builtin_amdgcn_s_barrier();
        if (t + 2 < KT) {
            g_stage_s(aP0, aP1, bP0, bP1, Abuf[0], Bbuf[0], w, bstep);
            asm volatile("s_waitcnt vmcnt(4)" ::: "memory");
        } else {
            asm volatile("s_waitcnt vmcnt(0)" ::: "memory");
        }
        __builtin_amdgcn_s_barrier();
        __builtin_amdgcn_sched_barrier(0);
        GEMM_COMPUTE_S(Abuf[1], Bbuf[1]);
        __builtin_amdgcn_s_barrier();
    }

    int rhi = (l >> 4) * 4;
    float bvv[4], scl[4];
#pragma unroll
    for (int ni = 0; ni < 4; ++ni) {
        int col = n0 + wn2 * 64 + ni * 16 + c16;
        bvv[ni] = bias[col];
        scl[ni] = (col < qcols) ? qscale : 1.0f;
    }
#pragma unroll
    for (int mi = 0; mi < 4; ++mi) {
#pragma unroll
        for (int r = 0; r < 4; ++r) {
            int row = m0 + wm2 * 64 + mi * 16 + rhi + r;
#pragma unroll
            for (int ni = 0; ni < 4; ++ni) {
                int col = n0 + wn2 * 64 + ni * 16 + c16;
                float v = (acc[mi][ni][r] + bvv[ni]) * scl[ni];
                if (ACT == 1) v = 0.5f * v * (1.0f + erff(v * 0.70710678118654752f));
                C[(size_t)row * N + col] = f2bf(v);
            }
        }
    }
}

// ----------------------------- conv0: K-split implicit GEMM -----------------
__device__ __forceinline__ void conv0_stage(
    const ushort* __restrict__ hb, const ushort* __restrict__ W,
    ushort* Abuf, ushort* Bbuf, int tid, int m0, int kk, int kt) {
    int r0 = tid >> 2;
    int kgrp = (((tid & 3) ^ ((tid >> 3) & 3)) << 3);
    int w = tid >> 6;
    int r = m0 + r0;
    int b1 = r / 37, t1 = r - b1 * 37;
    int tok1 = b1 * SEQL + 2 * t1 + kk;
    int r2 = r + 64;
    int b2 = r2 / 37, t2 = r2 - b2 * 37;
    int tok2 = b2 * SEQL + 2 * t2 + kk;
    const ushort* ga0 = hb + (size_t)tok1 * DMODEL + kt * 32 + kgrp;
    const ushort* ga1 = hb + (size_t)tok2 * DMODEL + kt * 32 + kgrp;
    ushort* la = Abuf + (w * 64) * 8;
    GLL(ga0, la);
    GLL(ga1, la + 2048);
    const ushort* Bk = W + (size_t)kk * 98304;
    int g0 = tid >> 7, nn0 = tid & 127;
    int li1 = 256 + tid;
    int g1 = li1 >> 7, nn1 = li1 & 127;
    ushort* lb = Bbuf + (w * 64) * 8;
    GLL(Bk + ((size_t)(kt * 4 + g0) * 128 + nn0) * 8, lb);
    GLL(Bk + ((size_t)(kt * 4 + g1) * 128 + nn1) * 8, lb + 2048);
}

__global__ __launch_bounds__(256) void conv0_part(
    const ushort* __restrict__ hb, const ushort* __restrict__ W,
    float* __restrict__ part) {
    __shared__ ushort Abuf[2][128 * 32];
    __shared__ ushort Bbuf[2][32 * 128];
    int m0 = blockIdx.x * 128;
    int kk = blockIdx.y;
    int tid = threadIdx.x;
    int w = tid >> 6, l = tid & 63;
    int wm = w >> 1, wn = w & 1;
    f32x4 acc[4][4];
#pragma unroll
    for (int i = 0; i < 4; ++i)
#pragma unroll
        for (int j = 0; j < 4; ++j)
            acc[i][j] = (f32x4){0.f, 0.f, 0.f, 0.f};

    conv0_stage(hb, W, Abuf[0], Bbuf[0], tid, m0, kk, 0);
    __syncthreads();
    int cur = 0;
    for (int s = 0; s < 24; ++s) {
        if (s + 1 < 24)
            conv0_stage(hb, W, Abuf[cur ^ 1], Bbuf[cur ^ 1], tid, m0, kk, s + 1);
        const char* Ab = (const char*)&Abuf[cur][0];
        const char* Bb = (const char*)&Bbuf[cur][0];
        bf16x8 af[4], bfv[4];
        int kg = l >> 4, c16 = l & 15;
#pragma unroll
        for (int mi = 0; mi < 4; ++mi) {
            int row = wm * 64 + mi * 16 + c16;
            int byt = row * 64 + ((kg ^ ((row >> 1) & 3)) << 4);
            af[mi] = *(const bf16x8*)(Ab + byt);
        }
#pragma unroll
        for (int ni = 0; ni < 4; ++ni) {
            int col = wn * 64 + ni * 16 + c16;
            int byt = kg * 2048 + col * 16;
            bfv[ni] = *(const bf16x8*)(Bb + byt);
        }
#pragma unroll
        for (int mi = 0; mi < 4; ++mi)
#pragma unroll
            for (int ni = 0; ni < 4; ++ni)
                acc[mi][ni] = __builtin_amdgcn_mfma_f32_16x16x32_bf16(
                    af[mi], bfv[ni], acc[mi][ni], 0, 0, 0);
        __syncthreads();
        cur ^= 1;
    }

    int c16 = l & 15, rhi = (l >> 4) * 4;
    float* pk = part + (size_t)kk * (9472 * 128);
#pragma unroll
    for (int mi = 0; mi < 4; ++mi) {
#pragma unroll
        for (int r = 0; r < 4; ++r) {
            int row = m0 + wm * 64 + mi * 16 + rhi + r;
#pragma unroll
            for (int ni = 0; ni < 4; ++ni) {
                int col = wn * 64 + ni * 16 + c16;
                pk[(size_t)row * 128 + col] = acc[mi][ni][r];
            }
        }
    }
}

__global__ __launch_bounds__(256) void conv0_reduce(
    const float* __restrict__ part, const float* __restrict__ cb,
    const float* __restrict__ g, const float* __restrict__ bb,
    const float* __restrict__ bm, const float* __restrict__ bv,
    float* __restrict__ out) {
    int idx = blockIdx.x * 256 + threadIdx.x;
    if (idx >= 9472 * 128) return;
    int row = idx >> 7, col = idx & 127;
    float a = 0.f;
#pragma unroll
    for (int kk = 0; kk < 8; ++kk) a += part[(size_t)kk * (9472 * 128) + idx];
    float scl = g[col] * rsqrtf(bv[col] + 1e-5f);
    float y = (a + cb[col] - bm[col]) * scl + bb[col];
    int b = row / 37, t = row - b * 37;
    out[(size_t)b * (128 * 37) + col * 37 + t] = fmaxf(y, 0.f);
}

// ----------------------------- MFMA fused attention -------------------------
__global__ __launch_bounds__(256) void attn_mfma(
    const ushort* __restrict__ qkv, ushort* __restrict__ o) {
    __shared__ ushort Qs[96 * 64];
    __shared__ ushort Ks[96 * 64];
    __shared__ ushort Vs[12 * 64 * 8];
    __shared__ ushort Ps[96 * 128];
    __shared__ float pmax[2][96];
    __shared__ float psum[2][96];

    int b = blockIdx.x / NH, h = blockIdx.x % NH;
    const ushort* qp = qkv + (size_t)b * SEQL * 2304 + h * HD;
    const ushort* kp = qp + 768;
    const ushort* vp = qp + 1536;

    int tid = threadIdx.x;
    int w = tid >> 6, l = tid & 63;
    int wm = w >> 1, wn = w & 1;
    int kg = l >> 4, c16 = l & 15;

    {
        int lrow = l >> 3, chunk = l & 7;
#pragma unroll
        for (int p = 0; p < 3; ++p) {
            int seg = p * 4 + w;
            int row = seg * 8 + lrow;
            int rowg = row < SEQL ? row : SEQL - 1;
            int sch = chunk ^ (row & 7);
            GLL(qp + (size_t)rowg * 2304 + sch * 8, Qs + seg * 512);
            GLL(kp + (size_t)rowg * 2304 + sch * 8, Ks + seg * 512);
        }
    }
#pragma unroll
    for (int p = 0; p < 3; ++p) {
        int t = p * 256 + tid;
        int key = t >> 3, dg = t & 7;
        int keyg = key < SEQL ? key : SEQL - 1;
        us8 vv = *(const us8*)(vp + (size_t)keyg * 2304 + dg * 8);
        int base = (key >> 3) * 512 + dg * 64 + (key & 7);
#pragma unroll
        for (int j = 0; j < 8; ++j) Vs[base + j * 8] = vv[j];
    }
    __syncthreads();

    f32x4 sacc[3][3];
#pragma unroll
    for (int i = 0; i < 3; ++i)
#pragma unroll
        for (int j = 0; j < 3; ++j) sacc[i][j] = (f32x4){0.f, 0.f, 0.f, 0.f};
    {
        const char* Qc = (const char*)Qs;
        const char* Kc = (const char*)Ks;
#pragma unroll
        for (int kt = 0; kt < 2; ++kt) {
            bf16x8 qa[3], ka[3];
#pragma unroll
            for (int mi = 0; mi < 3; ++mi) {
                int row = wm * 48 + mi * 16 + c16;
                qa[mi] = *(const bf16x8*)(Qc + row * 128 + (((kt * 4 + kg) ^ (row & 7)) << 4));
            }
#pragma unroll
            for (int ni = 0; ni < 3; ++ni) {
                int col = wn * 48 + ni * 16 + c16;
                ka[ni] = *(const bf16x8*)(Kc + col * 128 + (((kt * 4 + kg) ^ (col & 7)) << 4));
            }
#pragma unroll
            for (int mi = 0; mi < 3; ++mi)
#pragma unroll
                for (int ni = 0; ni < 3; ++ni)
                    sacc[mi][ni] = __builtin_amdgcn_mfma_f32_16x16x32_bf16(
                        qa[mi], ka[ni], sacc[mi][ni], 0, 0, 0);
        }
    }

#pragma unroll
    for (int mi = 0; mi < 3; ++mi) {
#pragma unroll
        for (int r = 0; r < 4; ++r) {
            float m = -3e30f;
#pragma unroll
            for (int ni = 0; ni < 3; ++ni) {
                int col = wn * 48 + ni * 16 + c16;
                float v = sacc[mi][ni][r];
                if (col >= SEQL) { v = -3e30f; sacc[mi][ni][r] = v; }
                m = fmaxf(m, v);
            }
#pragma unroll
            for (int off = 1; off < 16; off <<= 1) m = fmaxf(m, __shfl_xor(m, off, 64));
            if (c16 == 0) pmax[wn][wm * 48 + mi * 16 + kg * 4 + r] = m;
        }
    }
    __syncthreads();
#pragma unroll
    for (int mi = 0; mi < 3; ++mi) {
#pragma unroll
        for (int r = 0; r < 4; ++r) {
            int row = wm * 48 + mi * 16 + kg * 4 + r;
            float m = fmaxf(pmax[0][row], pmax[1][row]);
            float s = 0.f;
#pragma unroll
            for (int ni = 0; ni < 3; ++ni) {
                float pv = __expf(sacc[mi][ni][r] - m);
                sacc[mi][ni][r] = pv;
                s += pv;
            }
#pragma unroll
            for (int off = 1; off < 16; off <<= 1) s += __shfl_xor(s, off, 64);
            if (c16 == 0) psum[wn][row] = s;
#pragma unroll
            for (int ni = 0; ni < 3; ++ni) {
                int col = wn * 48 + ni * 16 + c16;
                Ps[row * 128 + ((((col >> 3) ^ (row & 7))) << 3) + (col & 7)] =
                    f2bf(sacc[mi][ni][r]);
            }
        }
    }
    __syncthreads();

    f32x4 oacc[3][2];
#pragma unroll
    for (int i = 0; i < 3; ++i)
#pragma unroll
        for (int j = 0; j < 2; ++j) oacc[i][j] = (f32x4){0.f, 0.f, 0.f, 0.f};
    {
        const char* Pc = (const char*)Ps;
        const char* Vc = (const char*)Vs;
#pragma unroll
        for (int ks = 0; ks < 3; ++ks) {
            bf16x8 pa[3], va[2];
#pragma unroll
            for (int mi = 0; mi < 3; ++mi) {
                int row = wm * 48 + mi * 16 + c16;
                pa[mi] = *(const bf16x8*)(Pc + row * 256 + (((ks * 4 + kg) ^ (row & 7)) << 4));
            }
#pragma unroll
            for (int ni = 0; ni < 2; ++ni) {
                int col = wn * 32 + ni * 16 + c16;
                va[ni] = *(const bf16x8*)(Vc + (ks * 4 + kg) * 1024 + col * 16);
            }
#pragma unroll
            for (int mi = 0; mi < 3; ++mi)
#pragma unroll
                for (int ni = 0; ni < 2; ++ni)
                    oacc[mi][ni] = __builtin_amdgcn_mfma_f32_16x16x32_bf16(
                        pa[mi], va[ni], oacc[mi][ni], 0, 0, 0);
        }
    }

#pragma unroll
    for (int mi = 0; mi < 3; ++mi) {
#pragma unroll
        for (int r = 0; r < 4; ++r) {
            int row = wm * 48 + mi * 16 + kg * 4 + r;
            if (row < SEQL) {
                float inv = 1.0f / (psum[0][row] + psum[1][row]);
                size_t obase = (size_t)(b * SEQL + row) * DMODEL + h * HD;
#pragma unroll
                for (int ni = 0; ni < 2; ++ni) {
                    int col = wn * 32 + ni * 16 + c16;
                    o[obase + col] = f2bf(oacc[mi][ni][r] * inv);
                }
            }
        }
    }
}

// ----------------------------- small conv tail -----------------------------
__global__ void conv1_kernel(const float* __restrict__ x, const float* __restrict__ w,
                             const float* __restrict__ cb, const float* __restrict__ g,
                             const float* __restrict__ bb, const float* __restrict__ bm,
                             const float* __restrict__ bv, float* __restrict__ out) {
    int idx = blockIdx.x * blockDim.x + threadIdx.x;
    if (idx >= BATCH * 64 * 14) return;
    int t = idx % 14, o = (idx / 14) % 64, b = idx / (14 * 64);
    float acc = cb[o];
    const float* wo = w + (long)o * 128 * 8;
    const float* xb = x + (long)b * 128 * 35;
    for (int c = 0; c < 128; ++c) {
#pragma unroll
        for (int kk = 0; kk < 8; ++kk)
            acc += xb[c * 35 + 2 * t + kk] * wo[c * 8 + kk];
    }
    float y = (acc - bm[o]) * g[o] * rsqrtf(bv[o] + 1e-5f) + bb[o];
    out[idx] = fmaxf(y, 0.0f);
}

__global__ void conv2_kernel(const float* __restrict__ x, const float* __restrict__ w,
                             const float* __restrict__ cb, const float* __restrict__ g,
                             const float* __restrict__ bb, const float* __restrict__ bm,
                             const float* __restrict__ bv, float* __restrict__ out) {
    int idx = blockIdx.x * blockDim.x + threadIdx.x;
    if (idx >= BATCH * 32 * 5) return;
    int t = idx % 5, o = (idx / 5) % 32, b = idx / (5 * 32);
    float acc = cb[o];
    const float* wo = w + (long)o * 64 * 3;
    const float* xb = x + (long)b * 64 * 12;
    for (int c = 0; c < 64; ++c) {
#pragma unroll
        for (int kk = 0; kk < 3; ++kk)
            acc += xb[c * 12 + 2 * t + kk] * wo[c * 3 + kk];
    }
    float y = (acc - bm[o]) * g[o] * rsqrtf(bv[o] + 1e-5f) + bb[o];
    out[idx] = fmaxf(y, 0.0f);
}

__global__ void pool_kernel(const float* __restrict__ in, float* __restrict__ out,
                            int C, int Tin) {
    int Tout = Tin - 2;
    int idx = blockIdx.x * blockDim.x + threadIdx.x;
    if (idx >= BATCH * C * Tout) return;
    int t = idx % Tout;
    int co = idx / Tout;
    const float* p = in + (long)co * Tin + t;
    out[idx] = fmaxf(fmaxf(p[0], p[1]), p[2]);
}

__global__ __launch_bounds__(64) void head_kernel(
    const float* __restrict__ x, const float* __restrict__ w1,
    const float* __restrict__ b1, const float* __restrict__ w2,
    const float* __restrict__ b2, float* __restrict__ out) {
    int b = blockIdx.x;
    int j = threadIdx.x;
    float y = 0.f;
    if (j < 32) {
        float acc = b1[j];
        const float* xb = x + b * 96;
        for (int i = 0; i < 96; ++i) acc += xb[i] * w1[j * 96 + i];
        y = fmaxf(acc, 0.0f) * w2[j];
    }
#pragma unroll
    for (int o = 32; o > 0; o >>= 1) y += __shfl_down(y, o, 64);
    if (j == 0) out[b] = 1.0f / (1.0f + expf(-(y + b2[0])));
}

// ----------------------------- launch -----------------------------
extern "C" void kernel_launch(void* const* d_in, const int* in_sizes, int n_in,
                              void* d_out, int out_size, void* d_ws, size_t ws_size,
                              hipStream_t stream) {
    const int*   ids  = (const int*)d_in[0];
    const float* wemb = (const float*)d_in[1];
    const float* pemb = (const float*)d_in[2];
    const float* elng = (const float*)d_in[3];
    const float* elnb = (const float*)d_in[4];
    const float* wq = (const float*)d_in[5];
    const float* bq = (const float*)d_in[6];
    const float* wk = (const float*)d_in[7];
    const float* bk = (const float*)d_in[8];
    const float* wv = (const float*)d_in[9];
    const float* bv = (const float*)d_in[10];
    const float* wo = (const float*)d_in[11];
    const float* bo = (const float*)d_in[12];
    const float* ln1g = (const float*)d_in[13];
    const float* ln1b = (const float*)d_in[14];
    const float* w1 = (const float*)d_in[15];
    const float* b1 = (const float*)d_in[16];
    const float* w2 = (const float*)d_in[17];
    const float* b2 = (const float*)d_in[18];
    const float* ln2g = (const float*)d_in[19];
    const float* ln2b = (const float*)d_in[20];
    const float* c0w = (const float*)d_in[21];
    const float* c0b = (const float*)d_in[22];
    const float* g0 = (const float*)d_in[23];
    const float* bb0 = (const float*)d_in[24];
    const float* m0 = (const float*)d_in[25];
    const float* v0 = (const float*)d_in[26];
    const float* c1w = (const float*)d_in[27];
    const float* c1b = (const float*)d_in[28];
    const float* g1 = (const float*)d_in[29];
    const float* bb1 = (const float*)d_in[30];
    const float* m1 = (const float*)d_in[31];
    const float* v1 = (const float*)d_in[32];
    const float* c2w = (const float*)d_in[33];
    const float* c2b = (const float*)d_in[34];
    const float* g2 = (const float*)d_in[35];
    const float* bb2 = (const float*)d_in[36];
    const float* m2 = (const float*)d_in[37];
    const float* v2 = (const float*)d_in[38];
    const float* d1w = (const float*)d_in[39];
    const float* d1b = (const float*)d_in[40];
    const float* d2w = (const float*)d_in[41];
    const float* d2b = (const float*)d_in[42];
    (void)in_sizes; (void)n_in; (void)out_size; (void)ws_size;

    const size_t SZ = (size_t)NTOK * DMODEL;
    char* p = (char*)d_ws;
    ushort* hb   = (ushort*)p; p += SZ * 2;
    ushort* qkvb = (ushort*)p; p += (size_t)NTOK * 2304 * 2;
    ushort* ob   = (ushort*)p; p += SZ * 2;
    ushort* rb   = (ushort*)p; p += SZ * 2;
    ushort* qkvw = (ushort*)p; p += (size_t)DMODEL * 2304 * 2;
    ushort* wob  = (ushort*)p; p += (size_t)DMODEL * DMODEL * 2;
    ushort* w1b  = (ushort*)p; p += (size_t)DMODEL * FFDIM * 2;
    ushort* w2b  = (ushort*)p; p += (size_t)FFDIM * DMODEL * 2;
    float*  cbias= (float*)p;  p += 2304 * 4;
    ushort* wc0  = (ushort*)p; p += (size_t)8 * 96 * 128 * 8 * 2;
    float* c0 = (float*)p;  p += (size_t)BATCH * 128 * 37 * 4;
    float* p0 = (float*)p;  p += (size_t)BATCH * 128 * 35 * 4;
    float* c1 = (float*)p;  p += (size_t)BATCH * 64 * 14 * 4;
    float* p1 = (float*)p;  p += (size_t)BATCH * 64 * 12 * 4;
    float* c2 = (float*)p;  p += (size_t)BATCH * 32 * 5 * 4;
    float* p2 = (float*)p;  p += (size_t)BATCH * 32 * 3 * 4;
    ushort* ff = (ushort*)p;
    float* part = (float*)qkvb;   // conv0 partials reuse dead qkv buffer

    embed_ln_kernel<<<NTOK, 256, 0, stream>>>(ids, wemb, pemb, elng, elnb, hb);
    convw_c0<<<(128 * 768 * 8 + 255) / 256, 256, 0, stream>>>(c0w, wc0);

    const int NWG_QKV = (NTOK / 256) * (2304 / 128);   // 81*18 = 1458
    const int NWG_WO  = (NTOK / 128) * (768 / 128);    // 162*6 = 972
    const int NWG_F1  = (NTOK / 256) * (FFDIM / 128);  // 81*24 = 1944
    const int NWG_F2  = (NTOK / 128) * (768 / 128);    // 972

    for (int l = 0; l < NLAYER; ++l) {
        convw_layer<<<4096, 256, 0, stream>>>(
            wq + (size_t)l * SQ1, wk + (size_t)l * SQ1, wv + (size_t)l * SQ1,
            wo + (size_t)l * SQ1, w1 + (size_t)l * SQ2, w2 + (size_t)l * SQ2,
            bq + (size_t)l * DMODEL, bk + (size_t)l * DMODEL, bv + (size_t)l * DMODEL,
            qkvw, wob, w1b, w2b, cbias);

        gemm_t<0><<<NWG_QKV, 512, 0, stream>>>(hb, qkvw, cbias, qkvb,
                                               NTOK, 2304, DMODEL, 0.125f, 768, 18);
        attn_mfma<<<BATCH * NH, 256, 0, stream>>>(qkvb, ob);
        gemm_s<0><<<NWG_WO, 256, 0, stream>>>(ob, wob, bo + (size_t)l * DMODEL, rb,
                                              NTOK, DMODEL, DMODEL, 1.0f, 0, 6);
        add_ln_kernel<<<NTOK, 192, 0, stream>>>(hb, rb, ln1g + (size_t)l * DMODEL,
                                                ln1b + (size_t)l * DMODEL);
        gemm_t<1><<<NWG_F1, 512, 0, stream>>>(hb, w1b, b1 + (size_t)l * FFDIM, ff,
                                              NTOK, FFDIM, DMODEL, 1.0f, 0, FFDIM / 128);
        gemm_s<0><<<NWG_F2, 256, 0, stream>>>(ff, w2b, b2 + (size_t)l * DMODEL, rb,
                                              NTOK, DMODEL, FFDIM, 1.0f, 0, 6);
        add_ln_kernel<<<NTOK, 192, 0, stream>>>(hb, rb, ln2g + (size_t)l * DMODEL,
                                                ln2b + (size_t)l * DMODEL);
    }

    // CNN / MLP head
    {
        conv0_part<<<dim3(74, 8), 256, 0, stream>>>(hb, wc0, part);
        conv0_reduce<<<(9472 * 128 + 255) / 256, 256, 0, stream>>>(part, c0b, g0, bb0, m0, v0, c0);
        int n = BATCH * 128 * 35;
        pool_kernel<<<(n + 255) / 256, 256, 0, stream>>>(c0, p0, 128, 37);
        n = BATCH * 64 * 14;
        conv1_kernel<<<(n + 255) / 256, 256, 0, stream>>>(p0, c1w, c1b, g1, bb1, m1, v1, c1);
        n = BATCH * 64 * 12;
        pool_kernel<<<(n + 255) / 256, 256, 0, stream>>>(c1, p1, 64, 14);
        n = BATCH * 32 * 5;
        conv2_kernel<<<(n + 255) / 256, 256, 0, stream>>>(p1, c2w, c2b, g2, bb2, m2, v2, c2);
        n = BATCH * 32 * 3;
        pool_kernel<<<(n + 255) / 256, 256, 0, stream>>>(c2, p2, 32, 5);
        head_kernel<<<BATCH, 64, 0, stream>>>(p2, d1w, d1b, d2w, d2b, (float*)d_out);
    }
}

// Round 15
// 5630.821 us; speedup vs baseline: 1.1301x; 1.1231x over previous
//
#include <hip/hip_runtime.h>
#include <hip/hip_bf16.h>

#define DMODEL 768
#define HD     64
#define NH     12
#define SEQL   81
#define BATCH  256
#define NTOK   (BATCH*SEQL)   /* 20736 */
#define FFDIM  3072
#define NLAYER 12

typedef __bf16 bf16x8 __attribute__((ext_vector_type(8)));
typedef float  f32x4  __attribute__((ext_vector_type(4)));
typedef unsigned short us8 __attribute__((ext_vector_type(8)));

__device__ __forceinline__ float bf2f(ushort u) {
    union { float f; unsigned u; } c; c.u = ((unsigned)u) << 16; return c.f;
}
__device__ __forceinline__ ushort f2bf(float f) {
    union { float f; unsigned u; } c; c.f = f;
    unsigned x = c.u;
    unsigned r = (x + 0x7fffu + ((x >> 16) & 1u)) >> 16;
    return (ushort)r;
}

#define GLL(gptr, lptr) __builtin_amdgcn_global_load_lds( \
    (const __attribute__((address_space(1))) void*)(gptr), \
    (__attribute__((address_space(3))) void*)(lptr), 16, 0, 0)

// ----------------------------- reductions -----------------------------
__device__ __forceinline__ float wave_sum(float v) {
#pragma unroll
    for (int o = 32; o > 0; o >>= 1) v += __shfl_down(v, o, 64);
    return v;
}

__device__ __forceinline__ void block_sum2_w4(float& a, float& b, float* red) {
    a = wave_sum(a); b = wave_sum(b);
    int lane = threadIdx.x & 63, wid = threadIdx.x >> 6;
    if (lane == 0) { red[wid] = a; red[4 + wid] = b; }
    __syncthreads();
    a = red[0] + red[1] + red[2] + red[3];
    b = red[4] + red[5] + red[6] + red[7];
    __syncthreads();
}
__device__ __forceinline__ void block_sum2_w3(float& a, float& b, float* red) {
    a = wave_sum(a); b = wave_sum(b);
    int lane = threadIdx.x & 63, wid = threadIdx.x >> 6;
    if (lane == 0) { red[wid] = a; red[3 + wid] = b; }
    __syncthreads();
    a = red[0] + red[1] + red[2];
    b = red[3] + red[4] + red[5];
    __syncthreads();
}

// ----------------------------- embedding + LN (bf16 out) --------------------
__global__ __launch_bounds__(256) void embed_ln_kernel(
    const int* __restrict__ ids, const float* __restrict__ wemb,
    const float* __restrict__ pemb, const float* __restrict__ g,
    const float* __restrict__ b, ushort* __restrict__ outb) {
    __shared__ float red[8];
    int tok = blockIdx.x;
    int s = tok % SEQL;
    long base = (long)ids[tok] * DMODEL;
    float vals[3];
    float sum = 0.f, sq = 0.f;
#pragma unroll
    for (int i = 0; i < 3; ++i) {
        int c = threadIdx.x + i * 256;
        float x = wemb[base + c] + pemb[s * DMODEL + c];
        vals[i] = x; sum += x; sq += x * x;
    }
    block_sum2_w4(sum, sq, red);
    float mean = sum * (1.0f / DMODEL);
    float inv = rsqrtf(sq * (1.0f / DMODEL) - mean * mean + 1e-5f);
#pragma unroll
    for (int i = 0; i < 3; ++i) {
        int c = threadIdx.x + i * 256;
        float y = (vals[i] - mean) * inv * g[c] + b[c];
        outb[(size_t)tok * DMODEL + c] = f2bf(y);
    }
}

// hb = bf16(LN(hb + r)); bf16 residual stream. 192 threads, ushort4.
__global__ __launch_bounds__(192) void add_ln_kernel(
    ushort* __restrict__ hb, const ushort* __restrict__ r,
    const float* __restrict__ g, const float* __restrict__ b) {
    __shared__ float red[6];
    size_t base = (size_t)blockIdx.x * DMODEL;
    int c = threadIdx.x * 4;
    ushort4 hv = *(const ushort4*)(hb + base + c);
    ushort4 rv = *(const ushort4*)(r + base + c);
    float vals[4];
    vals[0] = bf2f(hv.x) + bf2f(rv.x); vals[1] = bf2f(hv.y) + bf2f(rv.y);
    vals[2] = bf2f(hv.z) + bf2f(rv.z); vals[3] = bf2f(hv.w) + bf2f(rv.w);
    float sum = 0.f, sq = 0.f;
#pragma unroll
    for (int i = 0; i < 4; ++i) { sum += vals[i]; sq += vals[i] * vals[i]; }
    block_sum2_w3(sum, sq, red);
    float mean = sum * (1.0f / DMODEL);
    float inv = rsqrtf(sq * (1.0f / DMODEL) - mean * mean + 1e-5f);
    float4 gv = *(const float4*)(g + c);
    float4 bv = *(const float4*)(b + c);
    ushort4 ov;
    ov.x = f2bf((vals[0] - mean) * inv * gv.x + bv.x);
    ov.y = f2bf((vals[1] - mean) * inv * gv.y + bv.y);
    ov.z = f2bf((vals[2] - mean) * inv * gv.z + bv.z);
    ov.w = f2bf((vals[3] - mean) * inv * gv.w + bv.w);
    *(ushort4*)(hb + base + c) = ov;
}

// ----------------------------- weight conversion (per layer, fused) -----------
#define SQ1 589824                 /* 768*768 */
#define SQ2 2359296                /* 768*3072 */
#define CW_TOTAL (4*SQ1 + 2*SQ2 + 2304)
__global__ __launch_bounds__(256) void convw_layer(
    const float* __restrict__ wq, const float* __restrict__ wk,
    const float* __restrict__ wv, const float* __restrict__ wo,
    const float* __restrict__ w1, const float* __restrict__ w2,
    const float* __restrict__ bq, const float* __restrict__ bk,
    const float* __restrict__ bvp,
    ushort* __restrict__ qkvw, ushort* __restrict__ wob,
    ushort* __restrict__ w1b, ushort* __restrict__ w2b,
    float* __restrict__ cbias) {
    for (int i = blockIdx.x * 256 + threadIdx.x; i < CW_TOTAL; i += gridDim.x * 256) {
        if (i < 3 * SQ1) {
            int widx = i / SQ1, j = i - widx * SQ1;
            const float* src = widx == 0 ? wq : (widx == 1 ? wk : wv);
            int k = j / 768, n = j - k * 768;
            qkvw[(size_t)(k >> 3) * 2304 * 8 + (widx * 768 + n) * 8 + (k & 7)] = f2bf(src[j]);
        } else if (i < 4 * SQ1) {
            int j = i - 3 * SQ1;
            int k = j / 768, n = j - k * 768;
            wob[(size_t)(k >> 3) * 768 * 8 + n * 8 + (k & 7)] = f2bf(wo[j]);
        } else if (i < 4 * SQ1 + SQ2) {
            int j = i - 4 * SQ1;
            int k = j / 3072, n = j - k * 3072;
            w1b[(size_t)(k >> 3) * 3072 * 8 + n * 8 + (k & 7)] = f2bf(w1[j]);
        } else if (i < 4 * SQ1 + 2 * SQ2) {
            int j = i - 4 * SQ1 - SQ2;
            int k = j / 768, n = j - k * 768;
            w2b[(size_t)(k >> 3) * 768 * 8 + n * 8 + (k & 7)] = f2bf(w2[j]);
        } else {
            int j = i - 4 * SQ1 - 2 * SQ2;
            cbias[j] = j < 768 ? bq[j] : (j < 1536 ? bk[j - 768] : bvp[j - 1536]);
        }
    }
}

// conv0 weights: w[o][c][kk] fp32 -> dst[kk][(c>>3)*1024 + o*8 + (c&7)] bf16
__global__ __launch_bounds__(256) void convw_c0(
    const float* __restrict__ w, ushort* __restrict__ dst) {
    int idx = blockIdx.x * 256 + threadIdx.x;
    if (idx >= 128 * 768 * 8) return;
    int o = idx / 6144, rem = idx - o * 6144, c = rem >> 3, kk = rem & 7;
    dst[(size_t)kk * 98304 + (size_t)(c >> 3) * 1024 + o * 8 + (c & 7)] = f2bf(w[idx]);
}

// ----------------------------- 256x128 bf16 MFMA GEMM ------------------------
// 512 threads = 8 waves (4M x 2N), per-wave output 64x64 (acc 4x4). BK=32.
// LDS 48 KiB -> 3 blocks/CU. A tile: row-major [256][32], XOR key (row>>1)&3
// (2-way free); B tile [kg(4)][col(128)][8] (2-way free).
// Staging pointers precomputed per-thread, incremented per K-tile.
// Counted vmcnt(3) keeps next tile's loads in flight across barriers.
__device__ __forceinline__ void g_stage2(
    const ushort*& a0, const ushort*& a1, const ushort*& b0,
    ushort* Abuf, ushort* Bbuf, int w, size_t bstep) {
    GLL(a0, Abuf + (size_t)(w * 64) * 8);          a0 += 32;
    GLL(a1, Abuf + (size_t)(512 + w * 64) * 8);    a1 += 32;
    GLL(b0, Bbuf + (size_t)(w * 64) * 8);          b0 += bstep;
}

#define GEMM_COMPUTE(Ab_, Bb_)                                                 \
    {                                                                          \
        const char* Ab = (const char*)(Ab_);                                   \
        const char* Bb = (const char*)(Bb_);                                   \
        bf16x8 af[4], bfv[4];                                                  \
        _Pragma("unroll")                                                      \
        for (int mi = 0; mi < 4; ++mi) {                                       \
            int row = wm4 * 64 + mi * 16 + c16;                                \
            int byt = row * 64 + ((kg ^ ((row >> 1) & 3)) << 4);               \
            af[mi] = *(const bf16x8*)(Ab + byt);                               \
        }                                                                      \
        _Pragma("unroll")                                                      \
        for (int ni = 0; ni < 4; ++ni) {                                       \
            int col = wn2 * 64 + ni * 16 + c16;                                \
            bfv[ni] = *(const bf16x8*)(Bb + ((size_t)kg * 128 + col) * 16);    \
        }                                                                      \
        __builtin_amdgcn_s_setprio(1);                                         \
        _Pragma("unroll")                                                      \
        for (int mi = 0; mi < 4; ++mi)                                         \
            _Pragma("unroll")                                                  \
            for (int ni = 0; ni < 4; ++ni)                                     \
                acc[mi][ni] = __builtin_amdgcn_mfma_f32_16x16x32_bf16(         \
                    af[mi], bfv[ni], acc[mi][ni], 0, 0, 0);                    \
        __builtin_amdgcn_s_setprio(0);                                         \
    }

template <int ACT>
__global__ __launch_bounds__(512) void gemm_t(
    const ushort* __restrict__ A, const ushort* __restrict__ B,
    const float* __restrict__ bias, ushort* __restrict__ C,
    int M, int N, int K, float qscale, int qcols, int ntn) {
    __shared__ ushort Abuf[2][256 * 32];
    __shared__ ushort Bbuf[2][4 * 128 * 8];

    // bijective XCD swizzle (m204)
    int nblk = gridDim.x;
    int q = nblk >> 3, rr = nblk & 7;
    int xcd = blockIdx.x & 7, sub = blockIdx.x >> 3;
    int wg = (xcd < rr ? xcd * (q + 1) : rr * (q + 1) + (xcd - rr) * q) + sub;
    int mt = wg / ntn, nt = wg - mt * ntn;
    int m0 = mt * 256, n0 = nt * 128;

    int tid = threadIdx.x;
    int w = tid >> 6, l = tid & 63;
    int wm4 = w >> 1;                   // 0..3: M group of 64 rows
    int wn2 = w & 1;                    // 0..1: N group of 64 cols
    int kg = l >> 4, c16 = l & 15;

    // per-thread staging source pointers (computed once)
    const ushort *aP0, *aP1, *bP;
    {
        int r0 = tid >> 2, ch0 = tid & 3;
        aP0 = A + (size_t)(m0 + r0) * K + ((ch0 ^ ((r0 >> 1) & 3)) << 3);
        int ci1 = 512 + tid;
        int r1 = ci1 >> 2, ch1 = ci1 & 3;
        aP1 = A + (size_t)(m0 + r1) * K + ((ch1 ^ ((r1 >> 1) & 3)) << 3);
        int gg = tid >> 7, n = tid & 127;
        bP = B + ((size_t)gg * N + n0 + n) * 8;
    }
    const size_t bstep = (size_t)32 * N;

    f32x4 acc[4][4];
#pragma unroll
    for (int i = 0; i < 4; ++i)
#pragma unroll
        for (int j = 0; j < 4; ++j)
            acc[i][j] = (f32x4){0.f, 0.f, 0.f, 0.f};

    const int KT = K >> 5;              // always even (24 or 96)
    g_stage2(aP0, aP1, bP, Abuf[0], Bbuf[0], w, bstep);
    for (int t = 0; t < KT; t += 2) {
        g_stage2(aP0, aP1, bP, Abuf[1], Bbuf[1], w, bstep);
        asm volatile("s_waitcnt vmcnt(3)" ::: "memory");
        __builtin_amdgcn_s_barrier();
        __builtin_amdgcn_sched_barrier(0);
        GEMM_COMPUTE(Abuf[0], Bbuf[0]);
        __builtin_amdgcn_s_barrier();
        if (t + 2 < KT) {
            g_stage2(aP0, aP1, bP, Abuf[0], Bbuf[0], w, bstep);
            asm volatile("s_waitcnt vmcnt(3)" ::: "memory");
        } else {
            asm volatile("s_waitcnt vmcnt(0)" ::: "memory");
        }
        __builtin_amdgcn_s_barrier();
        __builtin_amdgcn_sched_barrier(0);
        GEMM_COMPUTE(Abuf[1], Bbuf[1]);
        __builtin_amdgcn_s_barrier();
    }

    // epilogue: row-outer, ni-inner -> each 128B line written contiguously
    int rhi = (l >> 4) * 4;
    float bvv[4], scl[4];
#pragma unroll
    for (int ni = 0; ni < 4; ++ni) {
        int col = n0 + wn2 * 64 + ni * 16 + c16;
        bvv[ni] = bias[col];
        scl[ni] = (col < qcols) ? qscale : 1.0f;
    }
#pragma unroll
    for (int mi = 0; mi < 4; ++mi) {
#pragma unroll
        for (int r = 0; r < 4; ++r) {
            int row = m0 + wm4 * 64 + mi * 16 + rhi + r;
#pragma unroll
            for (int ni = 0; ni < 4; ++ni) {
                int col = n0 + wn2 * 64 + ni * 16 + c16;
                float v = (acc[mi][ni][r] + bvv[ni]) * scl[ni];
                if (ACT == 1) v = 0.5f * v * (1.0f + erff(v * 0.70710678118654752f));
                C[(size_t)row * N + col] = f2bf(v);
            }
        }
    }
}

// ----------------------------- conv0: K-split implicit GEMM -----------------
__device__ __forceinline__ void conv0_stage(
    const ushort* __restrict__ hb, const ushort* __restrict__ W,
    ushort* Abuf, ushort* Bbuf, int tid, int m0, int kk, int kt) {
    int r0 = tid >> 2;
    int kgrp = (((tid & 3) ^ ((tid >> 3) & 3)) << 3);
    int w = tid >> 6;
    int r = m0 + r0;
    int b1 = r / 37, t1 = r - b1 * 37;
    int tok1 = b1 * SEQL + 2 * t1 + kk;
    int r2 = r + 64;
    int b2 = r2 / 37, t2 = r2 - b2 * 37;
    int tok2 = b2 * SEQL + 2 * t2 + kk;
    const ushort* ga0 = hb + (size_t)tok1 * DMODEL + kt * 32 + kgrp;
    const ushort* ga1 = hb + (size_t)tok2 * DMODEL + kt * 32 + kgrp;
    ushort* la = Abuf + (w * 64) * 8;
    GLL(ga0, la);
    GLL(ga1, la + 2048);
    const ushort* Bk = W + (size_t)kk * 98304;
    int g0 = tid >> 7, nn0 = tid & 127;
    int li1 = 256 + tid;
    int g1 = li1 >> 7, nn1 = li1 & 127;
    ushort* lb = Bbuf + (w * 64) * 8;
    GLL(Bk + ((size_t)(kt * 4 + g0) * 128 + nn0) * 8, lb);
    GLL(Bk + ((size_t)(kt * 4 + g1) * 128 + nn1) * 8, lb + 2048);
}

__global__ __launch_bounds__(256) void conv0_part(
    const ushort* __restrict__ hb, const ushort* __restrict__ W,
    float* __restrict__ part) {
    __shared__ ushort Abuf[2][128 * 32];
    __shared__ ushort Bbuf[2][32 * 128];
    int m0 = blockIdx.x * 128;
    int kk = blockIdx.y;
    int tid = threadIdx.x;
    int w = tid >> 6, l = tid & 63;
    int wm = w >> 1, wn = w & 1;
    f32x4 acc[4][4];
#pragma unroll
    for (int i = 0; i < 4; ++i)
#pragma unroll
        for (int j = 0; j < 4; ++j)
            acc[i][j] = (f32x4){0.f, 0.f, 0.f, 0.f};

    conv0_stage(hb, W, Abuf[0], Bbuf[0], tid, m0, kk, 0);
    __syncthreads();
    int cur = 0;
    for (int s = 0; s < 24; ++s) {
        if (s + 1 < 24)
            conv0_stage(hb, W, Abuf[cur ^ 1], Bbuf[cur ^ 1], tid, m0, kk, s + 1);
        const char* Ab = (const char*)&Abuf[cur][0];
        const char* Bb = (const char*)&Bbuf[cur][0];
        bf16x8 af[4], bfv[4];
        int kg = l >> 4, c16 = l & 15;
#pragma unroll
        for (int mi = 0; mi < 4; ++mi) {
            int row = wm * 64 + mi * 16 + c16;
            int byt = row * 64 + ((kg ^ ((row >> 1) & 3)) << 4);
            af[mi] = *(const bf16x8*)(Ab + byt);
        }
#pragma unroll
        for (int ni = 0; ni < 4; ++ni) {
            int col = wn * 64 + ni * 16 + c16;
            int byt = kg * 2048 + col * 16;
            bfv[ni] = *(const bf16x8*)(Bb + byt);
        }
#pragma unroll
        for (int mi = 0; mi < 4; ++mi)
#pragma unroll
            for (int ni = 0; ni < 4; ++ni)
                acc[mi][ni] = __builtin_amdgcn_mfma_f32_16x16x32_bf16(
                    af[mi], bfv[ni], acc[mi][ni], 0, 0, 0);
        __syncthreads();
        cur ^= 1;
    }

    int c16 = l & 15, rhi = (l >> 4) * 4;
    float* pk = part + (size_t)kk * (9472 * 128);
#pragma unroll
    for (int mi = 0; mi < 4; ++mi) {
#pragma unroll
        for (int r = 0; r < 4; ++r) {
            int row = m0 + wm * 64 + mi * 16 + rhi + r;
#pragma unroll
            for (int ni = 0; ni < 4; ++ni) {
                int col = wn * 64 + ni * 16 + c16;
                pk[(size_t)row * 128 + col] = acc[mi][ni][r];
            }
        }
    }
}

__global__ __launch_bounds__(256) void conv0_reduce(
    const float* __restrict__ part, const float* __restrict__ cb,
    const float* __restrict__ g, const float* __restrict__ bb,
    const float* __restrict__ bm, const float* __restrict__ bv,
    float* __restrict__ out) {
    int idx = blockIdx.x * 256 + threadIdx.x;
    if (idx >= 9472 * 128) return;
    int row = idx >> 7, col = idx & 127;
    float a = 0.f;
#pragma unroll
    for (int kk = 0; kk < 8; ++kk) a += part[(size_t)kk * (9472 * 128) + idx];
    float scl = g[col] * rsqrtf(bv[col] + 1e-5f);
    float y = (a + cb[col] - bm[col]) * scl + bb[col];
    int b = row / 37, t = row - b * 37;
    out[(size_t)b * (128 * 37) + col * 37 + t] = fmaxf(y, 0.f);
}

// ----------------------------- MFMA fused attention -------------------------
__global__ __launch_bounds__(256) void attn_mfma(
    const ushort* __restrict__ qkv, ushort* __restrict__ o) {
    __shared__ ushort Qs[96 * 64];
    __shared__ ushort Ks[96 * 64];
    __shared__ ushort Vs[12 * 64 * 8];
    __shared__ ushort Ps[96 * 128];
    __shared__ float pmax[2][96];
    __shared__ float psum[2][96];

    int b = blockIdx.x / NH, h = blockIdx.x % NH;
    const ushort* qp = qkv + (size_t)b * SEQL * 2304 + h * HD;
    const ushort* kp = qp + 768;
    const ushort* vp = qp + 1536;

    int tid = threadIdx.x;
    int w = tid >> 6, l = tid & 63;
    int wm = w >> 1, wn = w & 1;
    int kg = l >> 4, c16 = l & 15;

    {
        int lrow = l >> 3, chunk = l & 7;
#pragma unroll
        for (int p = 0; p < 3; ++p) {
            int seg = p * 4 + w;
            int row = seg * 8 + lrow;
            int rowg = row < SEQL ? row : SEQL - 1;
            int sch = chunk ^ (row & 7);
            GLL(qp + (size_t)rowg * 2304 + sch * 8, Qs + seg * 512);
            GLL(kp + (size_t)rowg * 2304 + sch * 8, Ks + seg * 512);
        }
    }
#pragma unroll
    for (int p = 0; p < 3; ++p) {
        int t = p * 256 + tid;
        int key = t >> 3, dg = t & 7;
        int keyg = key < SEQL ? key : SEQL - 1;
        us8 vv = *(const us8*)(vp + (size_t)keyg * 2304 + dg * 8);
        int base = (key >> 3) * 512 + dg * 64 + (key & 7);
#pragma unroll
        for (int j = 0; j < 8; ++j) Vs[base + j * 8] = vv[j];
    }
    __syncthreads();

    f32x4 sacc[3][3];
#pragma unroll
    for (int i = 0; i < 3; ++i)
#pragma unroll
        for (int j = 0; j < 3; ++j) sacc[i][j] = (f32x4){0.f, 0.f, 0.f, 0.f};
    {
        const char* Qc = (const char*)Qs;
        const char* Kc = (const char*)Ks;
#pragma unroll
        for (int kt = 0; kt < 2; ++kt) {
            bf16x8 qa[3], ka[3];
#pragma unroll
            for (int mi = 0; mi < 3; ++mi) {
                int row = wm * 48 + mi * 16 + c16;
                qa[mi] = *(const bf16x8*)(Qc + row * 128 + (((kt * 4 + kg) ^ (row & 7)) << 4));
            }
#pragma unroll
            for (int ni = 0; ni < 3; ++ni) {
                int col = wn * 48 + ni * 16 + c16;
                ka[ni] = *(const bf16x8*)(Kc + col * 128 + (((kt * 4 + kg) ^ (col & 7)) << 4));
            }
#pragma unroll
            for (int mi = 0; mi < 3; ++mi)
#pragma unroll
                for (int ni = 0; ni < 3; ++ni)
                    sacc[mi][ni] = __builtin_amdgcn_mfma_f32_16x16x32_bf16(
                        qa[mi], ka[ni], sacc[mi][ni], 0, 0, 0);
        }
    }

#pragma unroll
    for (int mi = 0; mi < 3; ++mi) {
#pragma unroll
        for (int r = 0; r < 4; ++r) {
            float m = -3e30f;
#pragma unroll
            for (int ni = 0; ni < 3; ++ni) {
                int col = wn * 48 + ni * 16 + c16;
                float v = sacc[mi][ni][r];
                if (col >= SEQL) { v = -3e30f; sacc[mi][ni][r] = v; }
                m = fmaxf(m, v);
            }
#pragma unroll
            for (int off = 1; off < 16; off <<= 1) m = fmaxf(m, __shfl_xor(m, off, 64));
            if (c16 == 0) pmax[wn][wm * 48 + mi * 16 + kg * 4 + r] = m;
        }
    }
    __syncthreads();
#pragma unroll
    for (int mi = 0; mi < 3; ++mi) {
#pragma unroll
        for (int r = 0; r < 4; ++r) {
            int row = wm * 48 + mi * 16 + kg * 4 + r;
            float m = fmaxf(pmax[0][row], pmax[1][row]);
            float s = 0.f;
#pragma unroll
            for (int ni = 0; ni < 3; ++ni) {
                float pv = __expf(sacc[mi][ni][r] - m);
                sacc[mi][ni][r] = pv;
                s += pv;
            }
#pragma unroll
            for (int off = 1; off < 16; off <<= 1) s += __shfl_xor(s, off, 64);
            if (c16 == 0) psum[wn][row] = s;
#pragma unroll
            for (int ni = 0; ni < 3; ++ni) {
                int col = wn * 48 + ni * 16 + c16;
                Ps[row * 128 + ((((col >> 3) ^ (row & 7))) << 3) + (col & 7)] =
                    f2bf(sacc[mi][ni][r]);
            }
        }
    }
    __syncthreads();

    f32x4 oacc[3][2];
#pragma unroll
    for (int i = 0; i < 3; ++i)
#pragma unroll
        for (int j = 0; j < 2; ++j) oacc[i][j] = (f32x4){0.f, 0.f, 0.f, 0.f};
    {
        const char* Pc = (const char*)Ps;
        const char* Vc = (const char*)Vs;
#pragma unroll
        for (int ks = 0; ks < 3; ++ks) {
            bf16x8 pa[3], va[2];
#pragma unroll
            for (int mi = 0; mi < 3; ++mi) {
                int row = wm * 48 + mi * 16 + c16;
                pa[mi] = *(const bf16x8*)(Pc + row * 256 + (((ks * 4 + kg) ^ (row & 7)) << 4));
            }
#pragma unroll
            for (int ni = 0; ni < 2; ++ni) {
                int col = wn * 32 + ni * 16 + c16;
                va[ni] = *(const bf16x8*)(Vc + (ks * 4 + kg) * 1024 + col * 16);
            }
#pragma unroll
            for (int mi = 0; mi < 3; ++mi)
#pragma unroll
                for (int ni = 0; ni < 2; ++ni)
                    oacc[mi][ni] = __builtin_amdgcn_mfma_f32_16x16x32_bf16(
                        pa[mi], va[ni], oacc[mi][ni], 0, 0, 0);
        }
    }

#pragma unroll
    for (int mi = 0; mi < 3; ++mi) {
#pragma unroll
        for (int r = 0; r < 4; ++r) {
            int row = wm * 48 + mi * 16 + kg * 4 + r;
            if (row < SEQL) {
                float inv = 1.0f / (psum[0][row] + psum[1][row]);
                size_t obase = (size_t)(b * SEQL + row) * DMODEL + h * HD;
#pragma unroll
                for (int ni = 0; ni < 2; ++ni) {
                    int col = wn * 32 + ni * 16 + c16;
                    o[obase + col] = f2bf(oacc[mi][ni][r] * inv);
                }
            }
        }
    }
}

// ----------------------------- small conv tail -----------------------------
__global__ void conv1_kernel(const float* __restrict__ x, const float* __restrict__ w,
                             const float* __restrict__ cb, const float* __restrict__ g,
                             const float* __restrict__ bb, const float* __restrict__ bm,
                             const float* __restrict__ bv, float* __restrict__ out) {
    int idx = blockIdx.x * blockDim.x + threadIdx.x;
    if (idx >= BATCH * 64 * 14) return;
    int t = idx % 14, o = (idx / 14) % 64, b = idx / (14 * 64);
    float acc = cb[o];
    const float* wo = w + (long)o * 128 * 8;
    const float* xb = x + (long)b * 128 * 35;
    for (int c = 0; c < 128; ++c) {
#pragma unroll
        for (int kk = 0; kk < 8; ++kk)
            acc += xb[c * 35 + 2 * t + kk] * wo[c * 8 + kk];
    }
    float y = (acc - bm[o]) * g[o] * rsqrtf(bv[o] + 1e-5f) + bb[o];
    out[idx] = fmaxf(y, 0.0f);
}

__global__ void conv2_kernel(const float* __restrict__ x, const float* __restrict__ w,
                             const float* __restrict__ cb, const float* __restrict__ g,
                             const float* __restrict__ bb, const float* __restrict__ bm,
                             const float* __restrict__ bv, float* __restrict__ out) {
    int idx = blockIdx.x * blockDim.x + threadIdx.x;
    if (idx >= BATCH * 32 * 5) return;
    int t = idx % 5, o = (idx / 5) % 32, b = idx / (5 * 32);
    float acc = cb[o];
    const float* wo = w + (long)o * 64 * 3;
    const float* xb = x + (long)b * 64 * 12;
    for (int c = 0; c < 64; ++c) {
#pragma unroll
        for (int kk = 0; kk < 3; ++kk)
            acc += xb[c * 12 + 2 * t + kk] * wo[c * 3 + kk];
    }
    float y = (acc - bm[o]) * g[o] * rsqrtf(bv[o] + 1e-5f) + bb[o];
    out[idx] = fmaxf(y, 0.0f);
}

__global__ void pool_kernel(const float* __restrict__ in, float* __restrict__ out,
                            int C, int Tin) {
    int Tout = Tin - 2;
    int idx = blockIdx.x * blockDim.x + threadIdx.x;
    if (idx >= BATCH * C * Tout) return;
    int t = idx % Tout;
    int co = idx / Tout;
    const float* p = in + (long)co * Tin + t;
    out[idx] = fmaxf(fmaxf(p[0], p[1]), p[2]);
}

__global__ __launch_bounds__(64) void head_kernel(
    const float* __restrict__ x, const float* __restrict__ w1,
    const float* __restrict__ b1, const float* __restrict__ w2,
    const float* __restrict__ b2, float* __restrict__ out) {
    int b = blockIdx.x;
    int j = threadIdx.x;
    float y = 0.f;
    if (j < 32) {
        float acc = b1[j];
        const float* xb = x + b * 96;
        for (int i = 0; i < 96; ++i) acc += xb[i] * w1[j * 96 + i];
        y = fmaxf(acc, 0.0f) * w2[j];
    }
#pragma unroll
    for (int o = 32; o > 0; o >>= 1) y += __shfl_down(y, o, 64);
    if (j == 0) out[b] = 1.0f / (1.0f + expf(-(y + b2[0])));
}

// ----------------------------- launch -----------------------------
extern "C" void kernel_launch(void* const* d_in, const int* in_sizes, int n_in,
                              void* d_out, int out_size, void* d_ws, size_t ws_size,
                              hipStream_t stream) {
    const int*   ids  = (const int*)d_in[0];
    const float* wemb = (const float*)d_in[1];
    const float* pemb = (const float*)d_in[2];
    const float* elng = (const float*)d_in[3];
    const float* elnb = (const float*)d_in[4];
    const float* wq = (const float*)d_in[5];
    const float* bq = (const float*)d_in[6];
    const float* wk = (const float*)d_in[7];
    const float* bk = (const float*)d_in[8];
    const float* wv = (const float*)d_in[9];
    const float* bv = (const float*)d_in[10];
    const float* wo = (const float*)d_in[11];
    const float* bo = (const float*)d_in[12];
    const float* ln1g = (const float*)d_in[13];
    const float* ln1b = (const float*)d_in[14];
    const float* w1 = (const float*)d_in[15];
    const float* b1 = (const float*)d_in[16];
    const float* w2 = (const float*)d_in[17];
    const float* b2 = (const float*)d_in[18];
    const float* ln2g = (const float*)d_in[19];
    const float* ln2b = (const float*)d_in[20];
    const float* c0w = (const float*)d_in[21];
    const float* c0b = (const float*)d_in[22];
    const float* g0 = (const float*)d_in[23];
    const float* bb0 = (const float*)d_in[24];
    const float* m0 = (const float*)d_in[25];
    const float* v0 = (const float*)d_in[26];
    const float* c1w = (const float*)d_in[27];
    const float* c1b = (const float*)d_in[28];
    const float* g1 = (const float*)d_in[29];
    const float* bb1 = (const float*)d_in[30];
    const float* m1 = (const float*)d_in[31];
    const float* v1 = (const float*)d_in[32];
    const float* c2w = (const float*)d_in[33];
    const float* c2b = (const float*)d_in[34];
    const float* g2 = (const float*)d_in[35];
    const float* bb2 = (const float*)d_in[36];
    const float* m2 = (const float*)d_in[37];
    const float* v2 = (const float*)d_in[38];
    const float* d1w = (const float*)d_in[39];
    const float* d1b = (const float*)d_in[40];
    const float* d2w = (const float*)d_in[41];
    const float* d2b = (const float*)d_in[42];
    (void)in_sizes; (void)n_in; (void)out_size; (void)ws_size;

    const size_t SZ = (size_t)NTOK * DMODEL;
    char* p = (char*)d_ws;
    ushort* hb   = (ushort*)p; p += SZ * 2;
    ushort* qkvb = (ushort*)p; p += (size_t)NTOK * 2304 * 2;
    ushort* ob   = (ushort*)p; p += SZ * 2;
    ushort* rb   = (ushort*)p; p += SZ * 2;
    ushort* qkvw = (ushort*)p; p += (size_t)DMODEL * 2304 * 2;
    ushort* wob  = (ushort*)p; p += (size_t)DMODEL * DMODEL * 2;
    ushort* w1b  = (ushort*)p; p += (size_t)DMODEL * FFDIM * 2;
    ushort* w2b  = (ushort*)p; p += (size_t)FFDIM * DMODEL * 2;
    float*  cbias= (float*)p;  p += 2304 * 4;
    ushort* wc0  = (ushort*)p; p += (size_t)8 * 96 * 128 * 8 * 2;
    float* c0 = (float*)p;  p += (size_t)BATCH * 128 * 37 * 4;
    float* p0 = (float*)p;  p += (size_t)BATCH * 128 * 35 * 4;
    float* c1 = (float*)p;  p += (size_t)BATCH * 64 * 14 * 4;
    float* p1 = (float*)p;  p += (size_t)BATCH * 64 * 12 * 4;
    float* c2 = (float*)p;  p += (size_t)BATCH * 32 * 5 * 4;
    float* p2 = (float*)p;  p += (size_t)BATCH * 32 * 3 * 4;
    ushort* ff = (ushort*)p;
    float* part = (float*)qkvb;   // conv0 partials reuse dead qkv buffer

    embed_ln_kernel<<<NTOK, 256, 0, stream>>>(ids, wemb, pemb, elng, elnb, hb);
    convw_c0<<<(128 * 768 * 8 + 255) / 256, 256, 0, stream>>>(c0w, wc0);

    const int NWG_QKV = (NTOK / 256) * (2304 / 128);   // 81*18 = 1458
    const int NWG_WO  = (NTOK / 256) * (768 / 128);    // 81*6  = 486
    const int NWG_F1  = (NTOK / 256) * (FFDIM / 128);  // 81*24 = 1944
    const int NWG_F2  = (NTOK / 256) * (768 / 128);    // 486

    for (int l = 0; l < NLAYER; ++l) {
        convw_layer<<<4096, 256, 0, stream>>>(
            wq + (size_t)l * SQ1, wk + (size_t)l * SQ1, wv + (size_t)l * SQ1,
            wo + (size_t)l * SQ1, w1 + (size_t)l * SQ2, w2 + (size_t)l * SQ2,
            bq + (size_t)l * DMODEL, bk + (size_t)l * DMODEL, bv + (size_t)l * DMODEL,
            qkvw, wob, w1b, w2b, cbias);

        gemm_t<0><<<NWG_QKV, 512, 0, stream>>>(hb, qkvw, cbias, qkvb,
                                               NTOK, 2304, DMODEL, 0.125f, 768, 18);
        attn_mfma<<<BATCH * NH, 256, 0, stream>>>(qkvb, ob);
        gemm_t<0><<<NWG_WO, 512, 0, stream>>>(ob, wob, bo + (size_t)l * DMODEL, rb,
                                              NTOK, DMODEL, DMODEL, 1.0f, 0, 6);
        add_ln_kernel<<<NTOK, 192, 0, stream>>>(hb, rb, ln1g + (size_t)l * DMODEL,
                                                ln1b + (size_t)l * DMODEL);
        gemm_t<1><<<NWG_F1, 512, 0, stream>>>(hb, w1b, b1 + (size_t)l * FFDIM, ff,
                                              NTOK, FFDIM, DMODEL, 1.0f, 0, FFDIM / 128);
        gemm_t<0><<<NWG_F2, 512, 0, stream>>>(ff, w2b, b2 + (size_t)l * DMODEL, rb,
                                              NTOK, DMODEL, FFDIM, 1.0f, 0, 6);
        add_ln_kernel<<<NTOK, 192, 0, stream>>>(hb, rb, ln2g + (size_t)l * DMODEL,
                                                ln2b + (size_t)l * DMODEL);
    }

    // CNN / MLP head
    {
        conv0_part<<<dim3(74, 8), 256, 0, stream>>>(hb, wc0, part);
        conv0_reduce<<<(9472 * 128 + 255) / 256, 256, 0, stream>>>(part, c0b, g0, bb0, m0, v0, c0);
        int n = BATCH * 128 * 35;
        pool_kernel<<<(n + 255) / 256, 256, 0, stream>>>(c0, p0, 128, 37);
        n = BATCH * 64 * 14;
        conv1_kernel<<<(n + 255) / 256, 256, 0, stream>>>(p0, c1w, c1b, g1, bb1, m1, v1, c1);
        n = BATCH * 64 * 12;
        pool_kernel<<<(n + 255) / 256, 256, 0, stream>>>(c1, p1, 64, 14);
        n = BATCH * 32 * 5;
        conv2_kernel<<<(n + 255) / 256, 256, 0, stream>>>(p1, c2w, c2b, g2, bb2, m2, v2, c2);
        n = BATCH * 32 * 3;
        pool_kernel<<<(n + 255) / 256, 256, 0, stream>>>(c2, p2, 32, 5);
        head_kernel<<<BATCH, 64, 0, stream>>>(p2, d1w, d1b, d2w, d2b, (float*)d_out);
    }
}

// Round 16
// 5446.955 us; speedup vs baseline: 1.1683x; 1.0338x over previous
//
#include <hip/hip_runtime.h>
#include <hip/hip_bf16.h>

#define DMODEL 768
#define HD     64
#define NH     12
#define SEQL   81
#define BATCH  256
#define NTOK   (BATCH*SEQL)   /* 20736 */
#define FFDIM  3072
#define NLAYER 12

typedef __bf16 bf16x8 __attribute__((ext_vector_type(8)));
typedef float  f32x4  __attribute__((ext_vector_type(4)));
typedef unsigned short us8 __attribute__((ext_vector_type(8)));

__device__ __forceinline__ float bf2f(ushort u) {
    union { float f; unsigned u; } c; c.u = ((unsigned)u) << 16; return c.f;
}
__device__ __forceinline__ ushort f2bf(float f) {
    union { float f; unsigned u; } c; c.f = f;
    unsigned x = c.u;
    unsigned r = (x + 0x7fffu + ((x >> 16) & 1u)) >> 16;
    return (ushort)r;
}

#define GLL(gptr, lptr) __builtin_amdgcn_global_load_lds( \
    (const __attribute__((address_space(1))) void*)(gptr), \
    (__attribute__((address_space(3))) void*)(lptr), 16, 0, 0)

// ----------------------------- reductions -----------------------------
__device__ __forceinline__ float wave_sum(float v) {
#pragma unroll
    for (int o = 32; o > 0; o >>= 1) v += __shfl_down(v, o, 64);
    return v;
}

__device__ __forceinline__ void block_sum2_w4(float& a, float& b, float* red) {
    a = wave_sum(a); b = wave_sum(b);
    int lane = threadIdx.x & 63, wid = threadIdx.x >> 6;
    if (lane == 0) { red[wid] = a; red[4 + wid] = b; }
    __syncthreads();
    a = red[0] + red[1] + red[2] + red[3];
    b = red[4] + red[5] + red[6] + red[7];
    __syncthreads();
}
__device__ __forceinline__ void block_sum2_w3(float& a, float& b, float* red) {
    a = wave_sum(a); b = wave_sum(b);
    int lane = threadIdx.x & 63, wid = threadIdx.x >> 6;
    if (lane == 0) { red[wid] = a; red[3 + wid] = b; }
    __syncthreads();
    a = red[0] + red[1] + red[2];
    b = red[3] + red[4] + red[5];
    __syncthreads();
}

// ----------------------------- embedding + LN (bf16 out) --------------------
__global__ __launch_bounds__(256) void embed_ln_kernel(
    const int* __restrict__ ids, const float* __restrict__ wemb,
    const float* __restrict__ pemb, const float* __restrict__ g,
    const float* __restrict__ b, ushort* __restrict__ outb) {
    __shared__ float red[8];
    int tok = blockIdx.x;
    int s = tok % SEQL;
    long base = (long)ids[tok] * DMODEL;
    float vals[3];
    float sum = 0.f, sq = 0.f;
#pragma unroll
    for (int i = 0; i < 3; ++i) {
        int c = threadIdx.x + i * 256;
        float x = wemb[base + c] + pemb[s * DMODEL + c];
        vals[i] = x; sum += x; sq += x * x;
    }
    block_sum2_w4(sum, sq, red);
    float mean = sum * (1.0f / DMODEL);
    float inv = rsqrtf(sq * (1.0f / DMODEL) - mean * mean + 1e-5f);
#pragma unroll
    for (int i = 0; i < 3; ++i) {
        int c = threadIdx.x + i * 256;
        float y = (vals[i] - mean) * inv * g[c] + b[c];
        outb[(size_t)tok * DMODEL + c] = f2bf(y);
    }
}

// hb = bf16(LN(hb + r)); bf16 residual stream. 192 threads, ushort4.
__global__ __launch_bounds__(192) void add_ln_kernel(
    ushort* __restrict__ hb, const ushort* __restrict__ r,
    const float* __restrict__ g, const float* __restrict__ b) {
    __shared__ float red[6];
    size_t base = (size_t)blockIdx.x * DMODEL;
    int c = threadIdx.x * 4;
    ushort4 hv = *(const ushort4*)(hb + base + c);
    ushort4 rv = *(const ushort4*)(r + base + c);
    float vals[4];
    vals[0] = bf2f(hv.x) + bf2f(rv.x); vals[1] = bf2f(hv.y) + bf2f(rv.y);
    vals[2] = bf2f(hv.z) + bf2f(rv.z); vals[3] = bf2f(hv.w) + bf2f(rv.w);
    float sum = 0.f, sq = 0.f;
#pragma unroll
    for (int i = 0; i < 4; ++i) { sum += vals[i]; sq += vals[i] * vals[i]; }
    block_sum2_w3(sum, sq, red);
    float mean = sum * (1.0f / DMODEL);
    float inv = rsqrtf(sq * (1.0f / DMODEL) - mean * mean + 1e-5f);
    float4 gv = *(const float4*)(g + c);
    float4 bv = *(const float4*)(b + c);
    ushort4 ov;
    ov.x = f2bf((vals[0] - mean) * inv * gv.x + bv.x);
    ov.y = f2bf((vals[1] - mean) * inv * gv.y + bv.y);
    ov.z = f2bf((vals[2] - mean) * inv * gv.z + bv.z);
    ov.w = f2bf((vals[3] - mean) * inv * gv.w + bv.w);
    *(ushort4*)(hb + base + c) = ov;
}

// ----------------------------- weight conversion (per layer, fused) -----------
// One thread per (kgroup, n): reads 8 fp32 (coalesced across threads), writes
// one aligned ushort8 (16B contiguous -> dense 1KB lines per wave).
// dst[kg*N*8 + n*8 + j] = bf16(W[kg*8+j][n])  ==  old (k>>3,k&7) layout.
#define SQ1 589824                 /* 768*768 */
#define SQ2 2359296                /* 768*3072 */
#define CWT0 221184                /* qkv: 96*2304 */
#define CWT1 294912                /* +wo: 96*768 */
#define CWT2 589824                /* +w1: 96*3072 */
#define CWT3 884736                /* +w2: 384*768 */
#define CWT4 887040                /* +bias 2304 */
__global__ __launch_bounds__(256) void convw_layer(
    const float* __restrict__ wq, const float* __restrict__ wk,
    const float* __restrict__ wv, const float* __restrict__ wo,
    const float* __restrict__ w1, const float* __restrict__ w2,
    const float* __restrict__ bq, const float* __restrict__ bk,
    const float* __restrict__ bvp,
    ushort* __restrict__ qkvw, ushort* __restrict__ wob,
    ushort* __restrict__ w1b, ushort* __restrict__ w2b,
    float* __restrict__ cbias) {
    int i = blockIdx.x * 256 + threadIdx.x;
    if (i >= CWT4) return;
    if (i < CWT0) {                       // qkv -> [kg][2304][8]
        int kg = i / 2304, n = i - kg * 2304;
        const float* src; int nn;
        if (n < 768)       { src = wq; nn = n; }
        else if (n < 1536) { src = wk; nn = n - 768; }
        else               { src = wv; nn = n - 1536; }
        us8 o;
#pragma unroll
        for (int j = 0; j < 8; ++j) o[j] = f2bf(src[(size_t)(kg * 8 + j) * 768 + nn]);
        *(us8*)(qkvw + ((size_t)kg * 2304 + n) * 8) = o;
    } else if (i < CWT1) {                // wo -> [kg][768][8]
        int t = i - CWT0;
        int kg = t / 768, n = t - kg * 768;
        us8 o;
#pragma unroll
        for (int j = 0; j < 8; ++j) o[j] = f2bf(wo[(size_t)(kg * 8 + j) * 768 + n]);
        *(us8*)(wob + ((size_t)kg * 768 + n) * 8) = o;
    } else if (i < CWT2) {                // w1 -> [kg][3072][8]
        int t = i - CWT1;
        int kg = t / 3072, n = t - kg * 3072;
        us8 o;
#pragma unroll
        for (int j = 0; j < 8; ++j) o[j] = f2bf(w1[(size_t)(kg * 8 + j) * 3072 + n]);
        *(us8*)(w1b + ((size_t)kg * 3072 + n) * 8) = o;
    } else if (i < CWT3) {                // w2 -> [kg][768][8]
        int t = i - CWT2;
        int kg = t / 768, n = t - kg * 768;
        us8 o;
#pragma unroll
        for (int j = 0; j < 8; ++j) o[j] = f2bf(w2[(size_t)(kg * 8 + j) * 768 + n]);
        *(us8*)(w2b + ((size_t)kg * 768 + n) * 8) = o;
    } else {                              // fused qkv bias
        int j = i - CWT3;
        cbias[j] = j < 768 ? bq[j] : (j < 1536 ? bk[j - 768] : bvp[j - 1536]);
    }
}

// conv0 weights: w[o][c][kk] fp32 -> dst[kk][(c>>3)*1024 + o*8 + (c&7)] bf16
__global__ __launch_bounds__(256) void convw_c0(
    const float* __restrict__ w, ushort* __restrict__ dst) {
    int idx = blockIdx.x * 256 + threadIdx.x;
    if (idx >= 128 * 768 * 8) return;
    int o = idx / 6144, rem = idx - o * 6144, c = rem >> 3, kk = rem & 7;
    dst[(size_t)kk * 98304 + (size_t)(c >> 3) * 1024 + o * 8 + (c & 7)] = f2bf(w[idx]);
}

// ----------------------------- 256x128 bf16 MFMA GEMM ------------------------
// 512 threads = 8 waves (4M x 2N), per-wave output 64x64 (acc 4x4). BK=32.
// LDS 48 KiB -> 3 blocks/CU. A tile: row-major [256][32], XOR key (row>>1)&3
// (2-way free); B tile [kg(4)][col(128)][8] (2-way free).
// Counted vmcnt(3) keeps next tile's loads in flight across barriers.
__device__ __forceinline__ void g_stage2(
    const ushort*& a0, const ushort*& a1, const ushort*& b0,
    ushort* Abuf, ushort* Bbuf, int w, size_t bstep) {
    GLL(a0, Abuf + (size_t)(w * 64) * 8);          a0 += 32;
    GLL(a1, Abuf + (size_t)(512 + w * 64) * 8);    a1 += 32;
    GLL(b0, Bbuf + (size_t)(w * 64) * 8);          b0 += bstep;
}

#define GEMM_COMPUTE(Ab_, Bb_)                                                 \
    {                                                                          \
        const char* Ab = (const char*)(Ab_);                                   \
        const char* Bb = (const char*)(Bb_);                                   \
        bf16x8 af[4], bfv[4];                                                  \
        _Pragma("unroll")                                                      \
        for (int mi = 0; mi < 4; ++mi) {                                       \
            int row = wm4 * 64 + mi * 16 + c16;                                \
            int byt = row * 64 + ((kg ^ ((row >> 1) & 3)) << 4);               \
            af[mi] = *(const bf16x8*)(Ab + byt);                               \
        }                                                                      \
        _Pragma("unroll")                                                      \
        for (int ni = 0; ni < 4; ++ni) {                                       \
            int col = wn2 * 64 + ni * 16 + c16;                                \
            bfv[ni] = *(const bf16x8*)(Bb + ((size_t)kg * 128 + col) * 16);    \
        }                                                                      \
        __builtin_amdgcn_s_setprio(1);                                         \
        _Pragma("unroll")                                                      \
        for (int mi = 0; mi < 4; ++mi)                                         \
            _Pragma("unroll")                                                  \
            for (int ni = 0; ni < 4; ++ni)                                     \
                acc[mi][ni] = __builtin_amdgcn_mfma_f32_16x16x32_bf16(         \
                    af[mi], bfv[ni], acc[mi][ni], 0, 0, 0);                    \
        __builtin_amdgcn_s_setprio(0);                                         \
    }

template <int ACT>
__global__ __launch_bounds__(512) void gemm_t(
    const ushort* __restrict__ A, const ushort* __restrict__ B,
    const float* __restrict__ bias, ushort* __restrict__ C,
    int M, int N, int K, float qscale, int qcols, int ntn) {
    __shared__ ushort Abuf[2][256 * 32];
    __shared__ ushort Bbuf[2][4 * 128 * 8];

    // bijective XCD swizzle (m204)
    int nblk = gridDim.x;
    int q = nblk >> 3, rr = nblk & 7;
    int xcd = blockIdx.x & 7, sub = blockIdx.x >> 3;
    int wg = (xcd < rr ? xcd * (q + 1) : rr * (q + 1) + (xcd - rr) * q) + sub;
    int mt = wg / ntn, nt = wg - mt * ntn;
    int m0 = mt * 256, n0 = nt * 128;

    int tid = threadIdx.x;
    int w = tid >> 6, l = tid & 63;
    int wm4 = w >> 1;                   // 0..3: M group of 64 rows
    int wn2 = w & 1;                    // 0..1: N group of 64 cols
    int kg = l >> 4, c16 = l & 15;

    // per-thread staging source pointers (computed once)
    const ushort *aP0, *aP1, *bP;
    {
        int r0 = tid >> 2, ch0 = tid & 3;
        aP0 = A + (size_t)(m0 + r0) * K + ((ch0 ^ ((r0 >> 1) & 3)) << 3);
        int ci1 = 512 + tid;
        int r1 = ci1 >> 2, ch1 = ci1 & 3;
        aP1 = A + (size_t)(m0 + r1) * K + ((ch1 ^ ((r1 >> 1) & 3)) << 3);
        int gg = tid >> 7, n = tid & 127;
        bP = B + ((size_t)gg * N + n0 + n) * 8;
    }
    const size_t bstep = (size_t)32 * N;

    f32x4 acc[4][4];
#pragma unroll
    for (int i = 0; i < 4; ++i)
#pragma unroll
        for (int j = 0; j < 4; ++j)
            acc[i][j] = (f32x4){0.f, 0.f, 0.f, 0.f};

    const int KT = K >> 5;              // always even (24 or 96)
    g_stage2(aP0, aP1, bP, Abuf[0], Bbuf[0], w, bstep);
    for (int t = 0; t < KT; t += 2) {
        g_stage2(aP0, aP1, bP, Abuf[1], Bbuf[1], w, bstep);
        asm volatile("s_waitcnt vmcnt(3)" ::: "memory");
        __builtin_amdgcn_s_barrier();
        __builtin_amdgcn_sched_barrier(0);
        GEMM_COMPUTE(Abuf[0], Bbuf[0]);
        __builtin_amdgcn_s_barrier();
        if (t + 2 < KT) {
            g_stage2(aP0, aP1, bP, Abuf[0], Bbuf[0], w, bstep);
            asm volatile("s_waitcnt vmcnt(3)" ::: "memory");
        } else {
            asm volatile("s_waitcnt vmcnt(0)" ::: "memory");
        }
        __builtin_amdgcn_s_barrier();
        __builtin_amdgcn_sched_barrier(0);
        GEMM_COMPUTE(Abuf[1], Bbuf[1]);
        __builtin_amdgcn_s_barrier();
    }

    // epilogue: row-outer, ni-inner -> each 128B line written contiguously
    int rhi = (l >> 4) * 4;
    float bvv[4], scl[4];
#pragma unroll
    for (int ni = 0; ni < 4; ++ni) {
        int col = n0 + wn2 * 64 + ni * 16 + c16;
        bvv[ni] = bias[col];
        scl[ni] = (col < qcols) ? qscale : 1.0f;
    }
#pragma unroll
    for (int mi = 0; mi < 4; ++mi) {
#pragma unroll
        for (int r = 0; r < 4; ++r) {
            int row = m0 + wm4 * 64 + mi * 16 + rhi + r;
#pragma unroll
            for (int ni = 0; ni < 4; ++ni) {
                int col = n0 + wn2 * 64 + ni * 16 + c16;
                float v = (acc[mi][ni][r] + bvv[ni]) * scl[ni];
                if (ACT == 1) v = 0.5f * v * (1.0f + erff(v * 0.70710678118654752f));
                C[(size_t)row * N + col] = f2bf(v);
            }
        }
    }
}

// ----------------------------- conv0: K-split implicit GEMM -----------------
__device__ __forceinline__ void conv0_stage(
    const ushort* __restrict__ hb, const ushort* __restrict__ W,
    ushort* Abuf, ushort* Bbuf, int tid, int m0, int kk, int kt) {
    int r0 = tid >> 2;
    int kgrp = (((tid & 3) ^ ((tid >> 3) & 3)) << 3);
    int w = tid >> 6;
    int r = m0 + r0;
    int b1 = r / 37, t1 = r - b1 * 37;
    int tok1 = b1 * SEQL + 2 * t1 + kk;
    int r2 = r + 64;
    int b2 = r2 / 37, t2 = r2 - b2 * 37;
    int tok2 = b2 * SEQL + 2 * t2 + kk;
    const ushort* ga0 = hb + (size_t)tok1 * DMODEL + kt * 32 + kgrp;
    const ushort* ga1 = hb + (size_t)tok2 * DMODEL + kt * 32 + kgrp;
    ushort* la = Abuf + (w * 64) * 8;
    GLL(ga0, la);
    GLL(ga1, la + 2048);
    const ushort* Bk = W + (size_t)kk * 98304;
    int g0 = tid >> 7, nn0 = tid & 127;
    int li1 = 256 + tid;
    int g1 = li1 >> 7, nn1 = li1 & 127;
    ushort* lb = Bbuf + (w * 64) * 8;
    GLL(Bk + ((size_t)(kt * 4 + g0) * 128 + nn0) * 8, lb);
    GLL(Bk + ((size_t)(kt * 4 + g1) * 128 + nn1) * 8, lb + 2048);
}

__global__ __launch_bounds__(256) void conv0_part(
    const ushort* __restrict__ hb, const ushort* __restrict__ W,
    float* __restrict__ part) {
    __shared__ ushort Abuf[2][128 * 32];
    __shared__ ushort Bbuf[2][32 * 128];
    int m0 = blockIdx.x * 128;
    int kk = blockIdx.y;
    int tid = threadIdx.x;
    int w = tid >> 6, l = tid & 63;
    int wm = w >> 1, wn = w & 1;
    f32x4 acc[4][4];
#pragma unroll
    for (int i = 0; i < 4; ++i)
#pragma unroll
        for (int j = 0; j < 4; ++j)
            acc[i][j] = (f32x4){0.f, 0.f, 0.f, 0.f};

    conv0_stage(hb, W, Abuf[0], Bbuf[0], tid, m0, kk, 0);
    __syncthreads();
    int cur = 0;
    for (int s = 0; s < 24; ++s) {
        if (s + 1 < 24)
            conv0_stage(hb, W, Abuf[cur ^ 1], Bbuf[cur ^ 1], tid, m0, kk, s + 1);
        const char* Ab = (const char*)&Abuf[cur][0];
        const char* Bb = (const char*)&Bbuf[cur][0];
        bf16x8 af[4], bfv[4];
        int kg = l >> 4, c16 = l & 15;
#pragma unroll
        for (int mi = 0; mi < 4; ++mi) {
            int row = wm * 64 + mi * 16 + c16;
            int byt = row * 64 + ((kg ^ ((row >> 1) & 3)) << 4);
            af[mi] = *(const bf16x8*)(Ab + byt);
        }
#pragma unroll
        for (int ni = 0; ni < 4; ++ni) {
            int col = wn * 64 + ni * 16 + c16;
            int byt = kg * 2048 + col * 16;
            bfv[ni] = *(const bf16x8*)(Bb + byt);
        }
#pragma unroll
        for (int mi = 0; mi < 4; ++mi)
#pragma unroll
            for (int ni = 0; ni < 4; ++ni)
                acc[mi][ni] = __builtin_amdgcn_mfma_f32_16x16x32_bf16(
                    af[mi], bfv[ni], acc[mi][ni], 0, 0, 0);
        __syncthreads();
        cur ^= 1;
    }

    int c16 = l & 15, rhi = (l >> 4) * 4;
    float* pk = part + (size_t)kk * (9472 * 128);
#pragma unroll
    for (int mi = 0; mi < 4; ++mi) {
#pragma unroll
        for (int r = 0; r < 4; ++r) {
            int row = m0 + wm * 64 + mi * 16 + rhi + r;
#pragma unroll
            for (int ni = 0; ni < 4; ++ni) {
                int col = wn * 64 + ni * 16 + c16;
                pk[(size_t)row * 128 + col] = acc[mi][ni][r];
            }
        }
    }
}

__global__ __launch_bounds__(256) void conv0_reduce(
    const float* __restrict__ part, const float* __restrict__ cb,
    const float* __restrict__ g, const float* __restrict__ bb,
    const float* __restrict__ bm, const float* __restrict__ bv,
    float* __restrict__ out) {
    int idx = blockIdx.x * 256 + threadIdx.x;
    if (idx >= 9472 * 128) return;
    int row = idx >> 7, col = idx & 127;
    float a = 0.f;
#pragma unroll
    for (int kk = 0; kk < 8; ++kk) a += part[(size_t)kk * (9472 * 128) + idx];
    float scl = g[col] * rsqrtf(bv[col] + 1e-5f);
    float y = (a + cb[col] - bm[col]) * scl + bb[col];
    int b = row / 37, t = row - b * 37;
    out[(size_t)b * (128 * 37) + col * 37 + t] = fmaxf(y, 0.f);
}

// ----------------------------- MFMA fused attention -------------------------
__global__ __launch_bounds__(256) void attn_mfma(
    const ushort* __restrict__ qkv, ushort* __restrict__ o) {
    __shared__ ushort Qs[96 * 64];
    __shared__ ushort Ks[96 * 64];
    __shared__ ushort Vs[12 * 64 * 8];
    __shared__ ushort Ps[96 * 128];
    __shared__ float pmax[2][96];
    __shared__ float psum[2][96];

    int b = blockIdx.x / NH, h = blockIdx.x % NH;
    const ushort* qp = qkv + (size_t)b * SEQL * 2304 + h * HD;
    const ushort* kp = qp + 768;
    const ushort* vp = qp + 1536;

    int tid = threadIdx.x;
    int w = tid >> 6, l = tid & 63;
    int wm = w >> 1, wn = w & 1;
    int kg = l >> 4, c16 = l & 15;

    {
        int lrow = l >> 3, chunk = l & 7;
#pragma unroll
        for (int p = 0; p < 3; ++p) {
            int seg = p * 4 + w;
            int row = seg * 8 + lrow;
            int rowg = row < SEQL ? row : SEQL - 1;
            int sch = chunk ^ (row & 7);
            GLL(qp + (size_t)rowg * 2304 + sch * 8, Qs + seg * 512);
            GLL(kp + (size_t)rowg * 2304 + sch * 8, Ks + seg * 512);
        }
    }
#pragma unroll
    for (int p = 0; p < 3; ++p) {
        int t = p * 256 + tid;
        int key = t >> 3, dg = t & 7;
        int keyg = key < SEQL ? key : SEQL - 1;
        us8 vv = *(const us8*)(vp + (size_t)keyg * 2304 + dg * 8);
        int base = (key >> 3) * 512 + dg * 64 + (key & 7);
#pragma unroll
        for (int j = 0; j < 8; ++j) Vs[base + j * 8] = vv[j];
    }
    __syncthreads();

    f32x4 sacc[3][3];
#pragma unroll
    for (int i = 0; i < 3; ++i)
#pragma unroll
        for (int j = 0; j < 3; ++j) sacc[i][j] = (f32x4){0.f, 0.f, 0.f, 0.f};
    {
        const char* Qc = (const char*)Qs;
        const char* Kc = (const char*)Ks;
#pragma unroll
        for (int kt = 0; kt < 2; ++kt) {
            bf16x8 qa[3], ka[3];
#pragma unroll
            for (int mi = 0; mi < 3; ++mi) {
                int row = wm * 48 + mi * 16 + c16;
                qa[mi] = *(const bf16x8*)(Qc + row * 128 + (((kt * 4 + kg) ^ (row & 7)) << 4));
            }
#pragma unroll
            for (int ni = 0; ni < 3; ++ni) {
                int col = wn * 48 + ni * 16 + c16;
                ka[ni] = *(const bf16x8*)(Kc + col * 128 + (((kt * 4 + kg) ^ (col & 7)) << 4));
            }
#pragma unroll
            for (int mi = 0; mi < 3; ++mi)
#pragma unroll
                for (int ni = 0; ni < 3; ++ni)
                    sacc[mi][ni] = __builtin_amdgcn_mfma_f32_16x16x32_bf16(
                        qa[mi], ka[ni], sacc[mi][ni], 0, 0, 0);
        }
    }

#pragma unroll
    for (int mi = 0; mi < 3; ++mi) {
#pragma unroll
        for (int r = 0; r < 4; ++r) {
            float m = -3e30f;
#pragma unroll
            for (int ni = 0; ni < 3; ++ni) {
                int col = wn * 48 + ni * 16 + c16;
                float v = sacc[mi][ni][r];
                if (col >= SEQL) { v = -3e30f; sacc[mi][ni][r] = v; }
                m = fmaxf(m, v);
            }
#pragma unroll
            for (int off = 1; off < 16; off <<= 1) m = fmaxf(m, __shfl_xor(m, off, 64));
            if (c16 == 0) pmax[wn][wm * 48 + mi * 16 + kg * 4 + r] = m;
        }
    }
    __syncthreads();
#pragma unroll
    for (int mi = 0; mi < 3; ++mi) {
#pragma unroll
        for (int r = 0; r < 4; ++r) {
            int row = wm * 48 + mi * 16 + kg * 4 + r;
            float m = fmaxf(pmax[0][row], pmax[1][row]);
            float s = 0.f;
#pragma unroll
            for (int ni = 0; ni < 3; ++ni) {
                float pv = __expf(sacc[mi][ni][r] - m);
                sacc[mi][ni][r] = pv;
                s += pv;
            }
#pragma unroll
            for (int off = 1; off < 16; off <<= 1) s += __shfl_xor(s, off, 64);
            if (c16 == 0) psum[wn][row] = s;
#pragma unroll
            for (int ni = 0; ni < 3; ++ni) {
                int col = wn * 48 + ni * 16 + c16;
                Ps[row * 128 + ((((col >> 3) ^ (row & 7))) << 3) + (col & 7)] =
                    f2bf(sacc[mi][ni][r]);
            }
        }
    }
    __syncthreads();

    f32x4 oacc[3][2];
#pragma unroll
    for (int i = 0; i < 3; ++i)
#pragma unroll
        for (int j = 0; j < 2; ++j) oacc[i][j] = (f32x4){0.f, 0.f, 0.f, 0.f};
    {
        const char* Pc = (const char*)Ps;
        const char* Vc = (const char*)Vs;
#pragma unroll
        for (int ks = 0; ks < 3; ++ks) {
            bf16x8 pa[3], va[2];
#pragma unroll
            for (int mi = 0; mi < 3; ++mi) {
                int row = wm * 48 + mi * 16 + c16;
                pa[mi] = *(const bf16x8*)(Pc + row * 256 + (((ks * 4 + kg) ^ (row & 7)) << 4));
            }
#pragma unroll
            for (int ni = 0; ni < 2; ++ni) {
                int col = wn * 32 + ni * 16 + c16;
                va[ni] = *(const bf16x8*)(Vc + (ks * 4 + kg) * 1024 + col * 16);
            }
#pragma unroll
            for (int mi = 0; mi < 3; ++mi)
#pragma unroll
                for (int ni = 0; ni < 2; ++ni)
                    oacc[mi][ni] = __builtin_amdgcn_mfma_f32_16x16x32_bf16(
                        pa[mi], va[ni], oacc[mi][ni], 0, 0, 0);
        }
    }

#pragma unroll
    for (int mi = 0; mi < 3; ++mi) {
#pragma unroll
        for (int r = 0; r < 4; ++r) {
            int row = wm * 48 + mi * 16 + kg * 4 + r;
            if (row < SEQL) {
                float inv = 1.0f / (psum[0][row] + psum[1][row]);
                size_t obase = (size_t)(b * SEQL + row) * DMODEL + h * HD;
#pragma unroll
                for (int ni = 0; ni < 2; ++ni) {
                    int col = wn * 32 + ni * 16 + c16;
                    o[obase + col] = f2bf(oacc[mi][ni][r] * inv);
                }
            }
        }
    }
}

// ----------------------------- small conv tail -----------------------------
__global__ void conv1_kernel(const float* __restrict__ x, const float* __restrict__ w,
                             const float* __restrict__ cb, const float* __restrict__ g,
                             const float* __restrict__ bb, const float* __restrict__ bm,
                             const float* __restrict__ bv, float* __restrict__ out) {
    int idx = blockIdx.x * blockDim.x + threadIdx.x;
    if (idx >= BATCH * 64 * 14) return;
    int t = idx % 14, o = (idx / 14) % 64, b = idx / (14 * 64);
    float acc = cb[o];
    const float* wo = w + (long)o * 128 * 8;
    const float* xb = x + (long)b * 128 * 35;
    for (int c = 0; c < 128; ++c) {
#pragma unroll
        for (int kk = 0; kk < 8; ++kk)
            acc += xb[c * 35 + 2 * t + kk] * wo[c * 8 + kk];
    }
    float y = (acc - bm[o]) * g[o] * rsqrtf(bv[o] + 1e-5f) + bb[o];
    out[idx] = fmaxf(y, 0.0f);
}

__global__ void conv2_kernel(const float* __restrict__ x, const float* __restrict__ w,
                             const float* __restrict__ cb, const float* __restrict__ g,
                             const float* __restrict__ bb, const float* __restrict__ bm,
                             const float* __restrict__ bv, float* __restrict__ out) {
    int idx = blockIdx.x * blockDim.x + threadIdx.x;
    if (idx >= BATCH * 32 * 5) return;
    int t = idx % 5, o = (idx / 5) % 32, b = idx / (5 * 32);
    float acc = cb[o];
    const float* wo = w + (long)o * 64 * 3;
    const float* xb = x + (long)b * 64 * 12;
    for (int c = 0; c < 64; ++c) {
#pragma unroll
        for (int kk = 0; kk < 3; ++kk)
            acc += xb[c * 12 + 2 * t + kk] * wo[c * 3 + kk];
    }
    float y = (acc - bm[o]) * g[o] * rsqrtf(bv[o] + 1e-5f) + bb[o];
    out[idx] = fmaxf(y, 0.0f);
}

__global__ void pool_kernel(const float* __restrict__ in, float* __restrict__ out,
                            int C, int Tin) {
    int Tout = Tin - 2;
    int idx = blockIdx.x * blockDim.x + threadIdx.x;
    if (idx >= BATCH * C * Tout) return;
    int t = idx % Tout;
    int co = idx / Tout;
    const float* p = in + (long)co * Tin + t;
    out[idx] = fmaxf(fmaxf(p[0], p[1]), p[2]);
}

__global__ __launch_bounds__(64) void head_kernel(
    const float* __restrict__ x, const float* __restrict__ w1,
    const float* __restrict__ b1, const float* __restrict__ w2,
    const float* __restrict__ b2, float* __restrict__ out) {
    int b = blockIdx.x;
    int j = threadIdx.x;
    float y = 0.f;
    if (j < 32) {
        float acc = b1[j];
        const float* xb = x + b * 96;
        for (int i = 0; i < 96; ++i) acc += xb[i] * w1[j * 96 + i];
        y = fmaxf(acc, 0.0f) * w2[j];
    }
#pragma unroll
    for (int o = 32; o > 0; o >>= 1) y += __shfl_down(y, o, 64);
    if (j == 0) out[b] = 1.0f / (1.0f + expf(-(y + b2[0])));
}

// ----------------------------- launch -----------------------------
extern "C" void kernel_launch(void* const* d_in, const int* in_sizes, int n_in,
                              void* d_out, int out_size, void* d_ws, size_t ws_size,
                              hipStream_t stream) {
    const int*   ids  = (const int*)d_in[0];
    const float* wemb = (const float*)d_in[1];
    const float* pemb = (const float*)d_in[2];
    const float* elng = (const float*)d_in[3];
    const float* elnb = (const float*)d_in[4];
    const float* wq = (const float*)d_in[5];
    const float* bq = (const float*)d_in[6];
    const float* wk = (const float*)d_in[7];
    const float* bk = (const float*)d_in[8];
    const float* wv = (const float*)d_in[9];
    const float* bv = (const float*)d_in[10];
    const float* wo = (const float*)d_in[11];
    const float* bo = (const float*)d_in[12];
    const float* ln1g = (const float*)d_in[13];
    const float* ln1b = (const float*)d_in[14];
    const float* w1 = (const float*)d_in[15];
    const float* b1 = (const float*)d_in[16];
    const float* w2 = (const float*)d_in[17];
    const float* b2 = (const float*)d_in[18];
    const float* ln2g = (const float*)d_in[19];
    const float* ln2b = (const float*)d_in[20];
    const float* c0w = (const float*)d_in[21];
    const float* c0b = (const float*)d_in[22];
    const float* g0 = (const float*)d_in[23];
    const float* bb0 = (const float*)d_in[24];
    const float* m0 = (const float*)d_in[25];
    const float* v0 = (const float*)d_in[26];
    const float* c1w = (const float*)d_in[27];
    const float* c1b = (const float*)d_in[28];
    const float* g1 = (const float*)d_in[29];
    const float* bb1 = (const float*)d_in[30];
    const float* m1 = (const float*)d_in[31];
    const float* v1 = (const float*)d_in[32];
    const float* c2w = (const float*)d_in[33];
    const float* c2b = (const float*)d_in[34];
    const float* g2 = (const float*)d_in[35];
    const float* bb2 = (const float*)d_in[36];
    const float* m2 = (const float*)d_in[37];
    const float* v2 = (const float*)d_in[38];
    const float* d1w = (const float*)d_in[39];
    const float* d1b = (const float*)d_in[40];
    const float* d2w = (const float*)d_in[41];
    const float* d2b = (const float*)d_in[42];
    (void)in_sizes; (void)n_in; (void)out_size; (void)ws_size;

    const size_t SZ = (size_t)NTOK * DMODEL;
    char* p = (char*)d_ws;
    ushort* hb   = (ushort*)p; p += SZ * 2;
    ushort* qkvb = (ushort*)p; p += (size_t)NTOK * 2304 * 2;
    ushort* ob   = (ushort*)p; p += SZ * 2;
    ushort* rb   = (ushort*)p; p += SZ * 2;
    ushort* qkvw = (ushort*)p; p += (size_t)DMODEL * 2304 * 2;
    ushort* wob  = (ushort*)p; p += (size_t)DMODEL * DMODEL * 2;
    ushort* w1b  = (ushort*)p; p += (size_t)DMODEL * FFDIM * 2;
    ushort* w2b  = (ushort*)p; p += (size_t)FFDIM * DMODEL * 2;
    float*  cbias= (float*)p;  p += 2304 * 4;
    ushort* wc0  = (ushort*)p; p += (size_t)8 * 96 * 128 * 8 * 2;
    float* c0 = (float*)p;  p += (size_t)BATCH * 128 * 37 * 4;
    float* p0 = (float*)p;  p += (size_t)BATCH * 128 * 35 * 4;
    float* c1 = (float*)p;  p += (size_t)BATCH * 64 * 14 * 4;
    float* p1 = (float*)p;  p += (size_t)BATCH * 64 * 12 * 4;
    float* c2 = (float*)p;  p += (size_t)BATCH * 32 * 5 * 4;
    float* p2 = (float*)p;  p += (size_t)BATCH * 32 * 3 * 4;
    ushort* ff = (ushort*)p;
    float* part = (float*)qkvb;   // conv0 partials reuse dead qkv buffer

    embed_ln_kernel<<<NTOK, 256, 0, stream>>>(ids, wemb, pemb, elng, elnb, hb);
    convw_c0<<<(128 * 768 * 8 + 255) / 256, 256, 0, stream>>>(c0w, wc0);

    const int NWG_QKV = (NTOK / 256) * (2304 / 128);   // 81*18 = 1458
    const int NWG_WO  = (NTOK / 256) * (768 / 128);    // 81*6  = 486
    const int NWG_F1  = (NTOK / 256) * (FFDIM / 128);  // 81*24 = 1944
    const int NWG_F2  = (NTOK / 256) * (768 / 128);    // 486
    const int NWG_CW  = (CWT4 + 255) / 256;            // 3465

    for (int l = 0; l < NLAYER; ++l) {
        convw_layer<<<NWG_CW, 256, 0, stream>>>(
            wq + (size_t)l * SQ1, wk + (size_t)l * SQ1, wv + (size_t)l * SQ1,
            wo + (size_t)l * SQ1, w1 + (size_t)l * SQ2, w2 + (size_t)l * SQ2,
            bq + (size_t)l * DMODEL, bk + (size_t)l * DMODEL, bv + (size_t)l * DMODEL,
            qkvw, wob, w1b, w2b, cbias);

        gemm_t<0><<<NWG_QKV, 512, 0, stream>>>(hb, qkvw, cbias, qkvb,
                                               NTOK, 2304, DMODEL, 0.125f, 768, 18);
        attn_mfma<<<BATCH * NH, 256, 0, stream>>>(qkvb, ob);
        gemm_t<0><<<NWG_WO, 512, 0, stream>>>(ob, wob, bo + (size_t)l * DMODEL, rb,
                                              NTOK, DMODEL, DMODEL, 1.0f, 0, 6);
        add_ln_kernel<<<NTOK, 192, 0, stream>>>(hb, rb, ln1g + (size_t)l * DMODEL,
                                                ln1b + (size_t)l * DMODEL);
        gemm_t<1><<<NWG_F1, 512, 0, stream>>>(hb, w1b, b1 + (size_t)l * FFDIM, ff,
                                              NTOK, FFDIM, DMODEL, 1.0f, 0, FFDIM / 128);
        gemm_t<0><<<NWG_F2, 512, 0, stream>>>(ff, w2b, b2 + (size_t)l * DMODEL, rb,
                                              NTOK, DMODEL, FFDIM, 1.0f, 0, 6);
        add_ln_kernel<<<NTOK, 192, 0, stream>>>(hb, rb, ln2g + (size_t)l * DMODEL,
                                                ln2b + (size_t)l * DMODEL);
    }

    // CNN / MLP head
    {
        conv0_part<<<dim3(74, 8), 256, 0, stream>>>(hb, wc0, part);
        conv0_reduce<<<(9472 * 128 + 255) / 256, 256, 0, stream>>>(part, c0b, g0, bb0, m0, v0, c0);
        int n = BATCH * 128 * 35;
        pool_kernel<<<(n + 255) / 256, 256, 0, stream>>>(c0, p0, 128, 37);
        n = BATCH * 64 * 14;
        conv1_kernel<<<(n + 255) / 256, 256, 0, stream>>>(p0, c1w, c1b, g1, bb1, m1, v1, c1);
        n = BATCH * 64 * 12;
        pool_kernel<<<(n + 255) / 256, 256, 0, stream>>>(c1, p1, 64, 14);
        n = BATCH * 32 * 5;
        conv2_kernel<<<(n + 255) / 256, 256, 0, stream>>>(p1, c2w, c2b, g2, bb2, m2, v2, c2);
        n = BATCH * 32 * 3;
        pool_kernel<<<(n + 255) / 256, 256, 0, stream>>>(c2, p2, 32, 5);
        head_kernel<<<BATCH, 64, 0, stream>>>(p2, d1w, d1b, d2w, d2b, (float*)d_out);
    }
}